// Round 8
// baseline (19291.672 us; speedup 1.0000x reference)
//
#include <hip/hip_runtime.h>
#include <cstddef>
#include <cstdint>
#include <math.h>

// ============================ constants ============================
static constexpr int NN   = 1024;   // lr_dim
static constexpr int HRD  = 2048;   // hr_dim
static constexpr int DIMF = 320;
static constexpr int TB   = 85;     // sytrd LDS tail block
static constexpr int CB3  = 128;    // persistent sytrd blocks (8 rows each)
static constexpr int BT3  = 1024;   // threads per sytrd block (16 waves)
static constexpr int NWY  = 16;     // WY reflector groups (64 each)

#define EPI_NONE      0
#define EPI_BIAS      1
#define EPI_BIAS_ADD  2
#define EPI_ABS_DIAG1 3
#define EPI_RELU      4

// agent-scope coherent access helpers (sc1).
__device__ __forceinline__ double gload(const double* p){
    return __hip_atomic_load(p, __ATOMIC_RELAXED, __HIP_MEMORY_SCOPE_AGENT);
}
__device__ __forceinline__ void gstore(double* p, double v){
    __hip_atomic_store(p, v, __ATOMIC_RELAXED, __HIP_MEMORY_SCOPE_AGENT);
}

// ============================ fp32 GEMM 64-tile (fallback, odd K) ============================
template<int EPI>
__global__ __launch_bounds__(256) void gemm32(
    const float* __restrict__ A, const float* __restrict__ B, float* __restrict__ C,
    int M, int N, int K, const float* __restrict__ bias, const float* __restrict__ D)
{
    __shared__ float As[16][65];
    __shared__ float Bs[16][65];
    const int bm = blockIdx.y << 6, bn = blockIdx.x << 6;
    const int tid = threadIdx.x;
    const int tm = (tid >> 4) << 2, tn = (tid & 15) << 2;
    float acc[4][4] = {};
    const int kt = (K + 15) >> 4;
    for (int k0 = 0; k0 < kt; ++k0){
        const int kb = k0 << 4;
        for (int t = tid; t < 1024; t += 256){
            int m = t >> 4, k = t & 15;
            int gm = bm + m, gk = kb + k;
            As[k][m] = (gm < M && gk < K) ? A[(size_t)gm*K + gk] : 0.f;
        }
        for (int t = tid; t < 1024; t += 256){
            int k = t >> 6, nn2 = t & 63;
            int gk = kb + k, gn = bn + nn2;
            Bs[k][nn2] = (gk < K && gn < N) ? B[(size_t)gk*N + gn] : 0.f;
        }
        __syncthreads();
        #pragma unroll
        for (int k = 0; k < 16; ++k){
            float a0 = As[k][tm], a1 = As[k][tm+1], a2 = As[k][tm+2], a3 = As[k][tm+3];
            float b0 = Bs[k][tn], b1 = Bs[k][tn+1], b2 = Bs[k][tn+2], b3 = Bs[k][tn+3];
            acc[0][0] += a0*b0; acc[0][1] += a0*b1; acc[0][2] += a0*b2; acc[0][3] += a0*b3;
            acc[1][0] += a1*b0; acc[1][1] += a1*b1; acc[1][2] += a1*b2; acc[1][3] += a1*b3;
            acc[2][0] += a2*b0; acc[2][1] += a2*b1; acc[2][2] += a2*b2; acc[2][3] += a2*b3;
            acc[3][0] += a3*b0; acc[3][1] += a3*b1; acc[3][2] += a3*b2; acc[3][3] += a3*b3;
        }
        __syncthreads();
    }
    #pragma unroll
    for (int r = 0; r < 4; ++r){
        int gm = bm + tm + r; if (gm >= M) continue;
        #pragma unroll
        for (int c = 0; c < 4; ++c){
            int gn = bn + tn + c; if (gn >= N) continue;
            float v = acc[r][c];
            if (EPI == EPI_BIAS)            v += bias[gn];
            else if (EPI == EPI_BIAS_ADD)   v += bias[gn] + D[(size_t)gm*N + gn];
            else if (EPI == EPI_ABS_DIAG1)  v = (gm == gn) ? 1.0f : fabsf(v);
            else if (EPI == EPI_RELU)       v = fmaxf(v, 0.0f);
            C[(size_t)gm*N + gn] = v;
        }
    }
}

// ============================ fp32 GEMM 64x128 double-buffered (K%16==0, N%8==0) ============================
template<int EPI>
__global__ __launch_bounds__(128) void gemm_db(
    const float* __restrict__ A, const float* __restrict__ B, float* __restrict__ C,
    int M, int N, int K, const float* __restrict__ bias, const float* __restrict__ D)
{
    __shared__ float As[2][16][68];
    __shared__ float Bs[2][16][132];
    const int bm = blockIdx.y << 6;
    const int bn = blockIdx.x << 7;
    const int tid = threadIdx.x;
    const int tm = (tid >> 4) << 3;
    const int tn = (tid & 15) << 3;
    const int ar = tid >> 2;
    const int af = tid & 3;
    const int br = tid >> 5;
    const int bf = tid & 31;

    float4 a_reg[2], b_reg[4];

    auto loadA = [&](int kb, int q) -> float4 {
        int gm = bm + ar + (q << 5);
        int gk = kb + (af << 2);
        if (gm < M) return *(const float4*)(A + (size_t)gm*K + gk);
        return make_float4(0.f,0.f,0.f,0.f);
    };
    auto loadB = [&](int kb, int q) -> float4 {
        int gk = kb + br + (q << 2);
        int gn = bn + (bf << 2);
        if (gn < N) return *(const float4*)(B + (size_t)gk*N + gn);
        return make_float4(0.f,0.f,0.f,0.f);
    };
    auto stash = [&](int p){
        #pragma unroll
        for (int q = 0; q < 2; ++q){
            int r = ar + (q << 5);
            As[p][(af<<2)+0][r] = a_reg[q].x; As[p][(af<<2)+1][r] = a_reg[q].y;
            As[p][(af<<2)+2][r] = a_reg[q].z; As[p][(af<<2)+3][r] = a_reg[q].w;
        }
        #pragma unroll
        for (int q = 0; q < 4; ++q)
            *(float4*)&Bs[p][br + (q<<2)][bf << 2] = b_reg[q];
    };

    #pragma unroll
    for (int q = 0; q < 2; ++q) a_reg[q] = loadA(0, q);
    #pragma unroll
    for (int q = 0; q < 4; ++q) b_reg[q] = loadB(0, q);
    stash(0);
    __syncthreads();

    float acc[8][8] = {};
    int p = 0;
    for (int kb = 16; ; kb += 16){
        const bool more = (kb < K);
        if (more){
            #pragma unroll
            for (int q = 0; q < 2; ++q) a_reg[q] = loadA(kb, q);
            #pragma unroll
            for (int q = 0; q < 4; ++q) b_reg[q] = loadB(kb, q);
        }
        #pragma unroll
        for (int k = 0; k < 16; ++k){
            float4 a0 = *(const float4*)&As[p][k][tm];
            float4 a1 = *(const float4*)&As[p][k][tm+4];
            float4 b0 = *(const float4*)&Bs[p][k][tn];
            float4 b1 = *(const float4*)&Bs[p][k][tn+4];
            float av[8] = {a0.x,a0.y,a0.z,a0.w,a1.x,a1.y,a1.z,a1.w};
            float bv[8] = {b0.x,b0.y,b0.z,b0.w,b1.x,b1.y,b1.z,b1.w};
            #pragma unroll
            for (int i = 0; i < 8; ++i)
                #pragma unroll
                for (int jj = 0; jj < 8; ++jj) acc[i][jj] += av[i]*bv[jj];
        }
        if (!more) break;
        stash(p ^ 1);
        __syncthreads();
        p ^= 1;
    }
    #pragma unroll
    for (int i = 0; i < 8; ++i){
        int gm = bm + tm + i; if (gm >= M) continue;
        #pragma unroll
        for (int jj = 0; jj < 8; ++jj){
            int gn = bn + tn + jj; if (gn >= N) continue;
            float v = acc[i][jj];
            if (EPI == EPI_BIAS)            v += bias[gn];
            else if (EPI == EPI_BIAS_ADD)   v += bias[gn] + D[(size_t)gm*N + gn];
            else if (EPI == EPI_ABS_DIAG1)  v = (gm == gn) ? 1.0f : fabsf(v);
            else if (EPI == EPI_RELU)       v = fmaxf(v, 0.0f);
            C[(size_t)gm*N + gn] = v;
        }
    }
}

// ============================ fp32 GEMM 128x128 double-buffered (K%16==0, N%8==0, big M) ============================
template<int EPI>
__global__ __launch_bounds__(256) void gemm128db(
    const float* __restrict__ A, const float* __restrict__ B, float* __restrict__ C,
    int M, int N, int K, const float* __restrict__ bias, const float* __restrict__ D)
{
    __shared__ float As[2][16][132];
    __shared__ float Bs[2][16][132];
    const int bm = blockIdx.y << 7, bn = blockIdx.x << 7;
    const int tid = threadIdx.x;
    const int tm = (tid >> 4) << 3;
    const int tn = (tid & 15) << 3;
    const int ar = tid >> 1;         // 0..127
    const int ak = (tid & 1) << 3;   // 0/8
    const int br = tid >> 4;         // 0..15
    const int bc = (tid & 15) << 3;  // 0..120

    float4 a0r, a1r, b0r, b1r;

    auto loadA = [&](int kb){
        int gm = bm + ar, gk = kb + ak;
        if (gm < M){
            const float* p = A + (size_t)gm*K + gk;
            a0r = *(const float4*)p; a1r = *(const float4*)(p + 4);
        } else { a0r = make_float4(0.f,0.f,0.f,0.f); a1r = a0r; }
    };
    auto loadB = [&](int kb){
        int gk = kb + br, gn = bn + bc;
        if (gn + 7 < N){
            const float* p = B + (size_t)gk*N + gn;
            b0r = *(const float4*)p; b1r = *(const float4*)(p + 4);
        } else {
            float t0[8];
            #pragma unroll
            for (int i = 0; i < 8; ++i){ int g2 = gn + i; t0[i] = (g2 < N) ? B[(size_t)gk*N + g2] : 0.f; }
            b0r = make_float4(t0[0],t0[1],t0[2],t0[3]); b1r = make_float4(t0[4],t0[5],t0[6],t0[7]);
        }
    };
    auto stash = [&](int p){
        As[p][ak+0][ar]=a0r.x; As[p][ak+1][ar]=a0r.y; As[p][ak+2][ar]=a0r.z; As[p][ak+3][ar]=a0r.w;
        As[p][ak+4][ar]=a1r.x; As[p][ak+5][ar]=a1r.y; As[p][ak+6][ar]=a1r.z; As[p][ak+7][ar]=a1r.w;
        *(float4*)&Bs[p][br][bc] = b0r; *(float4*)&Bs[p][br][bc+4] = b1r;
    };

    loadA(0); loadB(0); stash(0);
    __syncthreads();

    float acc[8][8] = {};
    int p = 0;
    for (int kb = 16; ; kb += 16){
        const bool more = (kb < K);
        if (more){ loadA(kb); loadB(kb); }
        #pragma unroll
        for (int k = 0; k < 16; ++k){
            float4 a0 = *(const float4*)&As[p][k][tm];
            float4 a1 = *(const float4*)&As[p][k][tm+4];
            float4 b0 = *(const float4*)&Bs[p][k][tn];
            float4 b1 = *(const float4*)&Bs[p][k][tn+4];
            float av[8] = {a0.x,a0.y,a0.z,a0.w,a1.x,a1.y,a1.z,a1.w};
            float bv[8] = {b0.x,b0.y,b0.z,b0.w,b1.x,b1.y,b1.z,b1.w};
            #pragma unroll
            for (int i = 0; i < 8; ++i)
                #pragma unroll
                for (int jj = 0; jj < 8; ++jj) acc[i][jj] += av[i]*bv[jj];
        }
        if (!more) break;
        stash(p ^ 1);
        __syncthreads();
        p ^= 1;
    }
    #pragma unroll
    for (int i = 0; i < 8; ++i){
        int gm = bm + tm + i; if (gm >= M) continue;
        #pragma unroll
        for (int jj = 0; jj < 8; ++jj){
            int gn = bn + tn + jj; if (gn >= N) continue;
            float v = acc[i][jj];
            if (EPI == EPI_BIAS)            v += bias[gn];
            else if (EPI == EPI_BIAS_ADD)   v += bias[gn] + D[(size_t)gm*N + gn];
            else if (EPI == EPI_ABS_DIAG1)  v = (gm == gn) ? 1.0f : fabsf(v);
            else if (EPI == EPI_RELU)       v = fmaxf(v, 0.0f);
            C[(size_t)gm*N + gn] = v;
        }
    }
}

// ============================ symmetric C = A @ A^T (B = A^T given), n%128==0 ============================
__global__ __launch_bounds__(256) void gemm_symAAT(
    const float* __restrict__ A, const float* __restrict__ Bt, float* __restrict__ C, int n)
{
    __shared__ float As[2][16][132];
    __shared__ float Bs[2][16][132];
    const int T = n >> 7;
    int ti = 0, rem = blockIdx.x;
    while (rem >= T - ti){ rem -= T - ti; ++ti; }
    const int tj = ti + rem;
    const int bm = ti << 7, bn = tj << 7;
    const int tid = threadIdx.x;
    const int tm = (tid >> 4) << 3;
    const int tn = (tid & 15) << 3;
    const int ar = tid >> 1;
    const int ak = (tid & 1) << 3;
    const int br = tid >> 4;
    const int bc = (tid & 15) << 3;

    float4 a0r, a1r, b0r, b1r;
    auto loadA = [&](int kb){
        const float* p = A + (size_t)(bm + ar)*n + kb + ak;
        a0r = *(const float4*)p; a1r = *(const float4*)(p + 4);
    };
    auto loadB = [&](int kb){
        const float* p = Bt + (size_t)(kb + br)*n + bn + bc;
        b0r = *(const float4*)p; b1r = *(const float4*)(p + 4);
    };
    auto stash = [&](int p){
        As[p][ak+0][ar]=a0r.x; As[p][ak+1][ar]=a0r.y; As[p][ak+2][ar]=a0r.z; As[p][ak+3][ar]=a0r.w;
        As[p][ak+4][ar]=a1r.x; As[p][ak+5][ar]=a1r.y; As[p][ak+6][ar]=a1r.z; As[p][ak+7][ar]=a1r.w;
        *(float4*)&Bs[p][br][bc] = b0r; *(float4*)&Bs[p][br][bc+4] = b1r;
    };

    loadA(0); loadB(0); stash(0);
    __syncthreads();

    float acc[8][8] = {};
    int p = 0;
    for (int kb = 16; ; kb += 16){
        const bool more = (kb < n);
        if (more){ loadA(kb); loadB(kb); }
        #pragma unroll
        for (int k = 0; k < 16; ++k){
            float4 a0 = *(const float4*)&As[p][k][tm];
            float4 a1 = *(const float4*)&As[p][k][tm+4];
            float4 b0 = *(const float4*)&Bs[p][k][tn];
            float4 b1 = *(const float4*)&Bs[p][k][tn+4];
            float av[8] = {a0.x,a0.y,a0.z,a0.w,a1.x,a1.y,a1.z,a1.w};
            float bv[8] = {b0.x,b0.y,b0.z,b0.w,b1.x,b1.y,b1.z,b1.w};
            #pragma unroll
            for (int i = 0; i < 8; ++i)
                #pragma unroll
                for (int jj = 0; jj < 8; ++jj) acc[i][jj] += av[i]*bv[jj];
        }
        if (!more) break;
        stash(p ^ 1);
        __syncthreads();
        p ^= 1;
    }
    #pragma unroll
    for (int i = 0; i < 8; ++i){
        #pragma unroll
        for (int jj = 0; jj < 8; ++jj)
            C[(size_t)(bm + tm + i)*n + (bn + tn + jj)] = acc[i][jj];
    }
    if (ti != tj){
        #pragma unroll
        for (int i = 0; i < 8; ++i)
            #pragma unroll
            for (int jj = 0; jj < 8; ++jj)
                C[(size_t)(bn + tn + jj)*n + (bm + tm + i)] = acc[i][jj];
    }
}

// ============================ small kernels ============================
__global__ __launch_bounds__(256) void rowsum_rsqrt_k(const float* __restrict__ lr, double* __restrict__ r64, int n)
{
    __shared__ double sm[256];
    int row = blockIdx.x;
    double s = 0.0;
    for (int j = threadIdx.x; j < n; j += 256) s += (double)lr[(size_t)row*n + j];
    sm[threadIdx.x] = s; __syncthreads();
    for (int o = 128; o; o >>= 1){ if (threadIdx.x < o) sm[threadIdx.x] += sm[threadIdx.x + o]; __syncthreads(); }
    if (threadIdx.x == 0){
        double t = sm[0];
        r64[row] = (t > 0.0) ? 1.0/sqrt(t) : 0.0;
    }
}

__global__ __launch_bounds__(256) void build_A_k(const float* __restrict__ lr, const double* __restrict__ r64,
                                                 float* __restrict__ A32, double* __restrict__ A64, int n)
{
    size_t idx = (size_t)blockIdx.x*256 + threadIdx.x;
    if (idx >= (size_t)n*n) return;
    int i = (int)(idx / n), j = (int)(idx % n);
    if (j < i) return;
    double v = (double)lr[(size_t)j*n + i] * r64[i] * r64[j];
    A64[(size_t)i*n + j] = v; A64[(size_t)j*n + i] = v;
    float vf = (float)v;
    A32[(size_t)i*n + j] = vf; A32[(size_t)j*n + i] = vf;
}

__global__ __launch_bounds__(256) void score_k(const float* __restrict__ X, const float* __restrict__ pw,
                                               const float* __restrict__ pb, float* __restrict__ out,
                                               int n, int dim)
{
    int row = blockIdx.x*4 + (threadIdx.x >> 6);
    int lane = threadIdx.x & 63;
    if (row >= n) return;
    float acc = 0.f;
    for (int c = lane; c < dim; c += 64) acc += X[(size_t)row*dim + c]*pw[c];
    #pragma unroll
    for (int o = 32; o; o >>= 1) acc += __shfl_down(acc, o);
    if (lane == 0){
        float t = (acc + pb[0]) * 0.01f;
        out[row] = 1.0f/(1.0f + expf(-t));
    }
}

// jax.lax.top_k semantics: descending value, ties -> lower index first
__global__ __launch_bounds__(256) void topk_k(const float* __restrict__ scores, int n, int k,
                                              int* __restrict__ idxo, float* __restrict__ valo)
{
    __shared__ float s[1024];
    int tid = threadIdx.x;
    for (int i = tid; i < n; i += 256) s[i] = scores[i];
    __syncthreads();
    for (int i = tid; i < n; i += 256){
        float si = s[i]; int r = 0;
        for (int j = 0; j < n; ++j){
            float sj = s[j];
            r += (sj > si) || (sj == si && j < i);
        }
        if (r < k){ idxo[r] = i; valo[r] = si; }
    }
}

__global__ __launch_bounds__(256) void gatherX_k(const float* __restrict__ X, const int* __restrict__ idx,
                                                 const float* __restrict__ vals, float* __restrict__ Xo,
                                                 int k, int dim)
{
    size_t t = (size_t)blockIdx.x*256 + threadIdx.x;
    if (t >= (size_t)k*dim) return;
    int m = (int)(t / dim), c = (int)(t % dim);
    Xo[t] = X[(size_t)idx[m]*dim + c] * vals[m];
}

__global__ __launch_bounds__(256) void scatterX_k(const float* __restrict__ Xs, const int* __restrict__ idx,
                                                  float* __restrict__ Xu, int k, int dim)
{
    size_t t = (size_t)blockIdx.x*256 + threadIdx.x;
    if (t >= (size_t)k*dim) return;
    int m = (int)(t / dim), c = (int)(t % dim);
    Xu[(size_t)idx[m]*dim + c] = Xs[t];
}

__global__ __launch_bounds__(256) void gatherA_k(const float* __restrict__ A, const int* __restrict__ idx,
                                                 float* __restrict__ Ao, int k, int n)
{
    size_t t = (size_t)blockIdx.x*256 + threadIdx.x;
    if (t >= (size_t)k*k) return;
    int m1 = (int)(t / k), m2 = (int)(t % k);
    Ao[t] = A[(size_t)idx[m1]*n + idx[m2]];
}

__global__ __launch_bounds__(256) void fill0_k(float* __restrict__ p, size_t cnt)
{
    size_t t = (size_t)blockIdx.x*256 + threadIdx.x;
    if (t < cnt) p[t] = 0.f;
}

__global__ __launch_bounds__(256) void filld0_k(double* __restrict__ p, size_t cnt)
{
    size_t t = (size_t)blockIdx.x*256 + threadIdx.x;
    if (t < cnt) p[t] = 0.0;
}

__global__ __launch_bounds__(256) void init_sytrd_k(double* __restrict__ pv, unsigned* __restrict__ bar, int n)
{
    int t = blockIdx.x*256 + threadIdx.x;
    if (t < n) pv[t] = 0.0;
    if (t < 1024) bar[t] = 0u;
}

__global__ __launch_bounds__(256) void concat_k(const float* __restrict__ X, const float* __restrict__ orgX,
                                                float* __restrict__ Xc, int n, int dim)
{
    size_t t = (size_t)blockIdx.x*256 + threadIdx.x;
    size_t tot = (size_t)n*2*dim;
    if (t >= tot) return;
    int i = (int)(t / (2*dim)), c = (int)(t % (2*dim));
    Xc[t] = (c < dim) ? X[(size_t)i*dim + c] : orgX[(size_t)i*dim + (c - dim)];
}

__global__ __launch_bounds__(256) void build_a_k(const float* __restrict__ gsr, float* __restrict__ a)
{
    size_t idx = (size_t)blockIdx.x*256 + threadIdx.x;
    if (idx >= (size_t)HRD*NN) return;
    int i = (int)(idx >> 10), k = (int)(idx & 1023);
    a[idx] = gsr[(size_t)i*HRD + k] + gsr[(size_t)i*HRD + NN + k];
}

__global__ __launch_bounds__(256) void symabs1_k(float* __restrict__ Z, int n)
{
    size_t idx = (size_t)blockIdx.x*256 + threadIdx.x;
    if (idx >= (size_t)n*n) return;
    int i = (int)(idx / n), j = (int)(idx % n);
    if (i > j) return;
    float a = Z[(size_t)i*n + j], b = Z[(size_t)j*n + i];
    float v = 0.5f*(a + b);
    float o = (i == j) ? 1.0f : fabsf(v);
    Z[(size_t)i*n + j] = o; Z[(size_t)j*n + i] = o;
}

__global__ __launch_bounds__(256) void final_z_k(const float* __restrict__ h2, float* __restrict__ z, int n)
{
    size_t idx = (size_t)blockIdx.x*256 + threadIdx.x;
    if (idx >= (size_t)n*n) return;
    int i = (int)(idx / n), j = (int)(idx % n);
    if (i > j) return;
    float v = 0.5f*(h2[(size_t)i*n + j] + h2[(size_t)j*n + i]);
    float o = (i == j) ? 1.0f : fabsf(v);
    z[(size_t)i*n + j] = o; z[(size_t)j*n + i] = o;
}

// dst[c][r] = (float)src[r][c]   (n x n, n % 32 == 0)
__global__ __launch_bounds__(256) void transpose_cast_k(const double* __restrict__ src, float* __restrict__ dst, int n)
{
    __shared__ float tile[32][33];
    int r0 = blockIdx.y*32, c0 = blockIdx.x*32;
    int tx = threadIdx.x & 31, ty = threadIdx.x >> 5;
    for (int i = ty; i < 32; i += 8)
        tile[i][tx] = (float)src[(size_t)(r0 + i)*n + (c0 + tx)];
    __syncthreads();
    for (int i = ty; i < 32; i += 8)
        dst[(size_t)(c0 + i)*n + (r0 + tx)] = tile[tx][i];
}

// dst[c][r] = src[r][c]  (n x n, n % 32 == 0)
__global__ __launch_bounds__(256) void transpose32_k(const float* __restrict__ src, float* __restrict__ dst, int n)
{
    __shared__ float tile[32][33];
    int r0 = blockIdx.y*32, c0 = blockIdx.x*32;
    int tx = threadIdx.x & 31, ty = threadIdx.x >> 5;
    for (int i = ty; i < 32; i += 8)
        tile[i][tx] = src[(size_t)(r0 + i)*n + (c0 + tx)];
    __syncthreads();
    for (int i = ty; i < 32; i += 8)
        dst[(size_t)(c0 + i)*n + (r0 + tx)] = tile[tx][i];
}

// ============================ persistent Householder tridiagonalization ============================
// sytrd_coop11 = coop8's PROVEN control skeleton (TREE barrier: per-group counters -> central;
// tid0-only arrival + spin; block-wide release __syncthreads) + the numerically-validated
// MERGED single-round phase-A reduction from coop10:
//   x_i = a_i + c2*b_i with a_i = rs_i - tau*p_i - (tau*p0)*vp_i, b_i = 2*vp_i (c2-independent);
//   one 4-value butterfly {S_pv, S_aa, S_ab, S_bb}; sigma2 = S_aa + 2c2*S_ab + c2^2*S_bb
//   (clamped >= 0); alpha = a_1 + c2*b_1.
// Round-7 A/B isolated the flat barrier as the regression (+~1.5 ms) and the merged
// reduction as a win (-~0.6 ms); this combines tree barrier + merged reduction.
__global__ __launch_bounds__(BT3) void sytrd_coop11(
    double* __restrict__ A, double* __restrict__ e, double* __restrict__ tauA,
    double* __restrict__ sclA, double* __restrict__ P,
    double* __restrict__ Rst, unsigned* __restrict__ bar, int n, int jend)
{
    __shared__ double VP[1024], WP[1024], VJ2[2][1024];
    __shared__ double red4[16][4];
    __shared__ double sh_a1, sh_b1;
    const int tid   = threadIdx.x;
    const int bid   = blockIdx.x;
    const int lane  = tid & 63;
    const int wid   = tid >> 6;
    const int rwav  = wid >> 1;
    const int half  = wid & 1;
    const int u     = (bid << 3) + rwav;
    const int g     = bid >> 4;            // barrier group (8 groups x 16 blocks)
    const int mylast = (bid << 3) + 7;
    const int cbase = half*64 + lane;

    double tau_p = 0.0, sc_p = 0.0;
    unsigned cumG = 0, cumC = 0;

    for (int j = 0; j < jend; ++j){
        const int m = n - 1 - j;
        double* __restrict__ VJnew = VJ2[j & 1];
        const double* __restrict__ VJold = VJ2[(j & 1) ^ 1];

        // barrier bookkeeping (pure function of j; all alive blocks agree)
        {
            const int retired = j >> 3;
            int d = retired - (g << 4);
            d = (d < 0) ? 0 : (d > 16 ? 16 : d);
            cumG += (unsigned)(16 - d);
            cumC += (unsigned)(8 - (j >> 7));
        }

        // ---- register-prefetch the owned trailing-row slots (overlaps phase-A sc1 round) ----
        double AR[8];
        double* __restrict__ Arow = A + (size_t)u*n + (j+1);
        if (u > j){
            #pragma unroll
            for (int q = 0; q < 8; ++q){
                int c = cbase + (q << 7);
                AR[q] = (c < m) ? Arow[c] : 0.0;
            }
        }

        // ---- fused phase A: ONE reduction round ----
        const bool act = (tid <= m);
        double a_ = 0.0, b_ = 0.0, pvp = 0.0, pi = 0.0, vp = 0.0, p0 = 0.0;
        if (j > 0){
            const double* __restrict__ Prow = P + (size_t)(j-1)*NN;
            const double* __restrict__ rs   = Rst + ((size_t)(j & 1) << 10);
            p0 = gload(&Prow[0]);
            if (act){
                pi = gload(&Prow[tid]);
                if (tid >= 1){
                    double rsi = gload(&rs[tid]);
                    vp = VJold[tid]*sc_p;
                    a_ = rsi - tau_p*pi - (tau_p*p0)*vp;
                    b_ = 2.0*vp;
                } else {
                    vp = 1.0;
                }
                pvp = pi*vp;
            }
        } else {
            if (act && tid >= 1){
                a_ = A[tid];   // row 0 col tid, fresh from build_A_k
                b_ = 0.0;
            }
        }
        if (tid == 1){ sh_a1 = a_; sh_b1 = b_; }
        double r0 = pvp;
        double r1 = (act && tid >= 2) ? a_*a_ : 0.0;
        double r2 = (act && tid >= 2) ? a_*b_ : 0.0;
        double r3 = (act && tid >= 2) ? b_*b_ : 0.0;
        #pragma unroll
        for (int o = 32; o; o >>= 1){
            r0 += __shfl_down(r0, o);
            r1 += __shfl_down(r1, o);
            r2 += __shfl_down(r2, o);
            r3 += __shfl_down(r3, o);
        }
        if (lane == 0){ red4[wid][0]=r0; red4[wid][1]=r1; red4[wid][2]=r2; red4[wid][3]=r3; }
        __syncthreads();     // sync1: red4 + sh_a1/sh_b1 visible

        double S_pv=0.0, S_aa=0.0, S_ab=0.0, S_bb=0.0;
        #pragma unroll
        for (int i = 0; i < 16; ++i){
            S_pv += red4[i][0]; S_aa += red4[i][1]; S_ab += red4[i][2]; S_bb += red4[i][3];
        }
        const double c2  = 0.5*tau_p*tau_p*S_pv;      // == 0 for j == 0
        const double wp0 = tau_p*p0 - c2;
        double sigma2 = S_aa + 2.0*c2*S_ab + c2*c2*S_bb;
        if (sigma2 < 0.0) sigma2 = 0.0;
        double alpha = sh_a1 + c2*sh_b1;
        double beta, tl, sc;
        if (sigma2 == 0.0){ beta = alpha; tl = 0.0; sc = 0.0; }
        else {
            beta = -copysign(sqrt(alpha*alpha + sigma2), alpha);
            tl = (beta - alpha)/beta;
            sc = 1.0/(alpha - beta);
        }

        // ---- elementwise writes (need c2) ----
        if (act){
            VP[tid] = vp;
            WP[tid] = tau_p*pi - c2*vp;
            if (tid >= 1) VJnew[tid-1] = a_ + c2*b_;
        }
        __syncthreads();     // sync2: VP/WP/VJnew visible

        // ---- owner-block writeback of row j ----
        if (bid == (j >> 3)){
            double* __restrict__ row = A + (size_t)j*n + (j+1);
            if (tid < m) row[tid] = VJnew[tid];
            if (tid == 0){
                e[j] = beta; tauA[j] = tl; sclA[j] = sc;
                if (j > 0) A[(size_t)j*n + j] -= 2.0*wp0;
            }
        }

        // ---- phase B: owner-private trailing update (from registers) + matvec; publish pivot ----
        if (u > j){
            const int r = u - (j+1);
            double* __restrict__ rs_w = Rst + ((size_t)((j+1) & 1) << 10);
            const bool pub = (r == 0);
            double acc = 0.0;
            if (j > 0){
                double vpr = VP[1+r], wpr = WP[1+r];
                #pragma unroll
                for (int q = 0; q < 8; ++q){
                    int c = cbase + (q << 7);
                    if (c < m){
                        double a = AR[q] - (vpr*WP[1+c] + wpr*VP[1+c]);
                        Arow[c] = a;
                        if (pub) gstore(&rs_w[c], a);
                        double vj = (c == 0) ? 1.0 : VJnew[c]*sc;
                        acc += a*vj;
                    }
                }
            } else {
                #pragma unroll
                for (int q = 0; q < 8; ++q){
                    int c = cbase + (q << 7);
                    if (c < m){
                        double a = AR[q];
                        if (pub) gstore(&rs_w[c], a);
                        double vj = (c == 0) ? 1.0 : VJnew[c]*sc;
                        acc += a*vj;
                    }
                }
            }
            #pragma unroll
            for (int o = 32; o; o >>= 1) acc += __shfl_down(acc, o);
            if (lane == 0)
                atomicAdd(&P[(size_t)j*NN + r], acc);
        }
        __syncthreads();     // sync3: each wave's vmcnt(0) drains its P atomics/Rst stores

        if (tid == 0){
            unsigned t = __hip_atomic_fetch_add(&bar[g*32], 1u, __ATOMIC_RELAXED, __HIP_MEMORY_SCOPE_AGENT);
            if (t == cumG - 1u)
                __hip_atomic_fetch_add(&bar[256], 1u, __ATOMIC_RELAXED, __HIP_MEMORY_SCOPE_AGENT);
            if (j != mylast){
                while (__hip_atomic_load(&bar[256], __ATOMIC_RELAXED, __HIP_MEMORY_SCOPE_AGENT) < cumC)
                    __builtin_amdgcn_s_sleep(1);
            }
        }
        if (j == mylast) break;    // retired (block-uniform; arrival already made)
        __syncthreads();           // sync4: release after spin (proven coop8 pattern)
        tau_p = tl; sc_p = sc;
    }

    // ---- final pending update (column jend-1) on the TB x TB tail, owner-only ----
    // Blocks bid >= jend>>3 never break -> VJ2/tau_p/sc_p live; P[jend-1] complete via last barrier.
    if (bid >= (jend >> 3)){
        const int tb = n - jend;
        const double* __restrict__ VJf = VJ2[(jend-1) & 1];
        const double* __restrict__ pp  = P + (size_t)(jend-1)*NN;
        double pvp = 0.0;
        if (tid < tb){
            double pi = gload(&pp[tid]);
            double v = (tid == 0) ? 1.0 : VJf[tid]*sc_p;
            pvp = pi*v;
        }
        #pragma unroll
        for (int o = 32; o; o >>= 1) pvp += __shfl_down(pvp, o);
        if (lane == 0) red4[wid][0] = pvp;
        __syncthreads();
        double pv = 0.0;
        #pragma unroll
        for (int i = 0; i < 16; ++i) pv += red4[i][0];
        double c2f = 0.5*tau_p*tau_p*pv;
        if (u >= jend){
            const int ri = u - jend;
            double vpr = (ri == 0) ? 1.0 : VJf[ri]*sc_p;
            double wpr = tau_p*gload(&pp[ri]) - c2f*vpr;
            double* __restrict__ Ar = A + (size_t)u*n + jend;
            for (int ci = half*64 + lane; ci < tb; ci += 128){
                double vpc = (ci == 0) ? 1.0 : VJf[ci]*sc_p;
                double wpc = tau_p*gload(&pp[ci]) - c2f*vpc;
                Ar[ci] -= vpr*wpc + wpr*vpc;
            }
        }
    }
}

// Tail: remaining (TB-2) Householder steps entirely in LDS (single block).
__global__ __launch_bounds__(256) void hh_tail(double* __restrict__ A64, double* __restrict__ e,
                                               double* __restrict__ tau, double* __restrict__ scaleg, int n)
{
    __shared__ double T[TB][TB+2];
    __shared__ double v[TB], p[TB], red[256];
    const int base = n - TB;
    const int tid = threadIdx.x;
    for (int t = tid; t < TB*TB; t += 256){
        int r = t / TB, c = t % TB;
        T[r][c] = A64[(size_t)(base + r)*n + base + c];
    }
    __syncthreads();
    for (int l = 0; l <= TB - 3; ++l){
        const int m = TB - 1 - l;
        double s = 0.0;
        for (int i = 1 + tid; i < m; i += 256){ double x = T[l+1+i][l]; s += x*x; }
        red[tid] = s; __syncthreads();
        for (int o = 128; o; o >>= 1){ if (tid < o) red[tid] += red[tid + o]; __syncthreads(); }
        double sigma2 = red[0];
        double alpha = T[l+1][l];
        double beta, tl, sc;
        if (sigma2 == 0.0){ beta = alpha; tl = 0.0; sc = 0.0; }
        else {
            beta = -copysign(sqrt(alpha*alpha + sigma2), alpha);
            tl = (beta - alpha)/beta;
            sc = 1.0/(alpha - beta);
        }
        for (int i = tid; i < m; i += 256) v[i] = (i == 0) ? 1.0 : T[l+1+i][l]*sc;
        __syncthreads();
        for (int i = tid; i < m; i += 256){
            double acc = 0.0;
            for (int c = 0; c < m; ++c) acc += T[l+1+i][l+1+c]*v[c];
            p[i] = acc;
        }
        __syncthreads();
        double s2 = 0.0;
        for (int i = tid; i < m; i += 256) s2 += p[i]*v[i];
        red[tid] = s2; __syncthreads();
        for (int o = 128; o; o >>= 1){ if (tid < o) red[tid] += red[tid + o]; __syncthreads(); }
        double pvv = red[0];
        double c2 = 0.5*tl*tl*pvv;
        for (int t2 = tid; t2 < m*m; t2 += 256){
            int r = t2 / m, c = t2 % m;
            double wr = tl*p[r] - c2*v[r];
            double wc = tl*p[c] - c2*v[c];
            T[l+1+r][l+1+c] -= v[r]*wc + wr*v[c];
        }
        if (tid == 0){ int j = base + l; e[j] = beta; tau[j] = tl; scaleg[j] = 1.0; }
        for (int i = tid; i < m; i += 256) A64[(size_t)(base + l)*n + (base + l + 1) + i] = v[i];
        __syncthreads();
    }
    for (int r = tid; r < TB; r += 256) A64[(size_t)(base + r)*n + base + r] = T[r][r];
    if (tid == 0) A64[(size_t)(n-1)*n + (n-2)] = T[TB-1][TB-2];
}

__global__ __launch_bounds__(256) void extract_de_k(const double* __restrict__ A64, double* __restrict__ d,
                                                    double* __restrict__ e, int n)
{
    int i = blockIdx.x*256 + threadIdx.x;
    if (i < n) d[i] = A64[(size_t)i*n + i];
    if (i == 0) e[n-2] = A64[(size_t)(n-1)*n + (n-2)];
}

// ============================ tridiagonal eigensolver ============================
__global__ __launch_bounds__(256) void bisect_k(const double* __restrict__ d, const double* __restrict__ e,
                                                double* __restrict__ w, int n)
{
    __shared__ double ds[1024], e2s[1024];
    const int tid = threadIdx.x;
    for (int i = tid; i < n; i += 256) ds[i] = d[i];
    for (int i = tid; i < n-1; i += 256){ double ei = e[i]; e2s[i] = ei*ei; }
    __syncthreads();
    int k = blockIdx.x*256 + tid;
    if (k >= n) return;
    double gl = 1e300, gu = -1e300;
    for (int i = 0; i < n; ++i){
        double em = (i > 0) ? sqrt(e2s[i-1]) : 0.0, ep2 = (i < n-1) ? sqrt(e2s[i]) : 0.0;
        double lo2 = ds[i] - em - ep2, hi2 = ds[i] + em + ep2;
        gl = fmin(gl, lo2); gu = fmax(gu, hi2);
    }
    double lo = gl - 1e-10, hi = gu + 1e-10;
    for (int it = 0; it < 42; ++it){
        double mid = 0.5*(lo + hi);
        int cnt = 0;
        double p0 = 1.0;
        double p1 = ds[0] - mid;
        if (p1 <= 0.0){ ++cnt; if (p1 == 0.0) p1 = -1e-300; }
        for (int i = 1; i < n; ++i){
            double pn = (ds[i] - mid)*p1 - e2s[i-1]*p0;
            bool neg = ((pn < 0.0) != (p1 < 0.0)) || (pn == 0.0);
            cnt += neg;
            if (pn == 0.0) pn = (p1 > 0.0) ? -1e-300 : 1e-300;
            p0 = p1; p1 = pn;
            double ap = fabs(p1);
            if (ap > 1e120){ p1 *= 1e-200; p0 *= 1e-200; }
            else if (ap < 1e-120){ p1 *= 1e200; p0 *= 1e200; }
        }
        if (cnt <= k) lo = mid; else hi = mid;
    }
    w[k] = 0.5*(lo + hi);
}

// Inverse iteration; 16-deep load prefetch in the dependent solve passes.
__global__ __launch_bounds__(256) void invit_k(const double* __restrict__ d, const double* __restrict__ e,
                                               const double* __restrict__ w,
                                               double* __restrict__ FD, double* __restrict__ FL,
                                               double* __restrict__ FU, double* __restrict__ FU2,
                                               signed char* __restrict__ PIV, double* __restrict__ Z, int n)
{
    __shared__ double dsm[1024], esm[1024];
    const int tid = threadIdx.x;
    for (int i = tid; i < n; i += 256) dsm[i] = d[i];
    for (int i = tid; i < n-1; i += 256) esm[i] = e[i];
    __syncthreads();
    int k = blockIdx.x*256 + tid;
    if (k >= n) return;
    const double lam = w[k];
    const double tiny = 1e-280;
    double dcur = dsm[0] - lam;
    double ucur = esm[0];
    for (int i = 0; i < n-1; ++i){
        double dli = esm[i];
        double dnext_init = dsm[i+1] - lam;
        double unext_init = (i < n-2) ? esm[i+1] : 0.0;
        size_t o = (size_t)i*n + k;
        if (fabs(dcur) >= fabs(dli)){
            if (dcur == 0.0) dcur = tiny;
            double f = dli/dcur;
            FD[o] = dcur; FL[o] = f; FU[o] = ucur; FU2[o] = 0.0; PIV[o] = 0;
            dcur = dnext_init - f*ucur;
            ucur = unext_init;
        } else {
            double f = dcur/dli;
            FD[o] = dli; FL[o] = f; FU[o] = dnext_init; FU2[o] = unext_init; PIV[o] = 1;
            dcur = ucur - f*dnext_init;
            ucur = -f*unext_init;
        }
    }
    if (dcur == 0.0) dcur = tiny;
    FD[(size_t)(n-1)*n + k] = dcur;
    for (int i = 0; i < n; ++i){
        unsigned h = (unsigned)(i + 1)*0x9E3779B9u + (unsigned)(k + 1)*0x85EBCA6Bu;
        h ^= h >> 16; h *= 0x7FEB352Du; h ^= h >> 15; h *= 0x846CA68Bu; h ^= h >> 16;
        Z[(size_t)i*n + k] = (double)(h >> 8)*(1.0/16777216.0) - 0.5;
    }
    const double fdlast = FD[(size_t)(n-1)*n + k];
    for (int iter = 0; iter < 2; ++iter){
        // ---- forward substitution (prefetch-16) ----
        double zc = Z[k];
        int i = 0;
        const int nm1 = n - 1;
        for (; i + 16 <= nm1; i += 16){
            double fl[16], zn[16]; int pv[16];
            #pragma unroll
            for (int u2 = 0; u2 < 16; ++u2){
                size_t o = (size_t)(i+u2)*n + k;
                fl[u2] = FL[o]; zn[u2] = Z[o + n]; pv[u2] = PIV[o];
            }
            #pragma unroll
            for (int u2 = 0; u2 < 16; ++u2){
                size_t o = (size_t)(i+u2)*n + k;
                if (!pv[u2]){ Z[o] = zc; zc = zn[u2] - fl[u2]*zc; }
                else        { Z[o] = zn[u2]; zc = zc - fl[u2]*zn[u2]; }
            }
        }
        for (; i < nm1; ++i){
            size_t o = (size_t)i*n + k;
            double fl = FL[o], zn = Z[o + n];
            if (!PIV[o]){ Z[o] = zc; zc = zn - fl*zc; }
            else        { Z[o] = zn; zc = zc - fl*zn; }
        }
        // ---- backward substitution (prefetch-16) ----
        double za = zc / fdlast;
        Z[(size_t)(n-1)*n + k] = za;
        size_t o2 = (size_t)(n-2)*n + k;
        double zaa = (Z[o2] - FU[o2]*za) / FD[o2];
        Z[o2] = zaa;
        double zb = za;
        int i2 = n - 3;
        for (; i2 >= 15; i2 -= 16){
            double zv[16], fu[16], fu2v[16], fd[16];
            #pragma unroll
            for (int u2 = 0; u2 < 16; ++u2){
                size_t o = (size_t)(i2-u2)*n + k;
                zv[u2] = Z[o]; fu[u2] = FU[o]; fu2v[u2] = FU2[o]; fd[u2] = FD[o];
            }
            #pragma unroll
            for (int u2 = 0; u2 < 16; ++u2){
                size_t o = (size_t)(i2-u2)*n + k;
                double znew = (zv[u2] - fu[u2]*zaa - fu2v[u2]*zb) / fd[u2];
                Z[o] = znew;
                zb = zaa; zaa = znew;
            }
        }
        for (; i2 >= 0; --i2){
            size_t o = (size_t)i2*n + k;
            double znew = (Z[o] - FU[o]*zaa - FU2[o]*zb) / FD[o];
            Z[o] = znew;
            zb = zaa; zaa = znew;
        }
        // ---- max-normalize (prefetch-8) ----
        double m0=0,m1=0,m2=0,m3=0,m4=0,m5=0,m6=0,m7=0;
        int i3 = 0;
        for (; i3 + 8 <= n; i3 += 8){
            m0 = fmax(m0, fabs(Z[(size_t)(i3+0)*n + k]));
            m1 = fmax(m1, fabs(Z[(size_t)(i3+1)*n + k]));
            m2 = fmax(m2, fabs(Z[(size_t)(i3+2)*n + k]));
            m3 = fmax(m3, fabs(Z[(size_t)(i3+3)*n + k]));
            m4 = fmax(m4, fabs(Z[(size_t)(i3+4)*n + k]));
            m5 = fmax(m5, fabs(Z[(size_t)(i3+5)*n + k]));
            m6 = fmax(m6, fabs(Z[(size_t)(i3+6)*n + k]));
            m7 = fmax(m7, fabs(Z[(size_t)(i3+7)*n + k]));
        }
        double mx = fmax(fmax(fmax(m0,m1),fmax(m2,m3)), fmax(fmax(m4,m5),fmax(m6,m7)));
        for (; i3 < n; ++i3) mx = fmax(mx, fabs(Z[(size_t)i3*n + k]));
        double s = (mx > 0.0) ? 1.0/mx : 1.0;
        for (int i4 = 0; i4 + 8 <= n; i4 += 8){
            double zv[8];
            #pragma unroll
            for (int u2 = 0; u2 < 8; ++u2) zv[u2] = Z[(size_t)(i4+u2)*n + k];
            #pragma unroll
            for (int u2 = 0; u2 < 8; ++u2) Z[(size_t)(i4+u2)*n + k] = zv[u2]*s;
        }
    }
    // ---- 2-norm normalize (prefetch-8) ----
    double n0=0,n1=0,n2=0,n3=0,n4=0,n5=0,n6=0,n7=0;
    int i5 = 0;
    for (; i5 + 8 <= n; i5 += 8){
        double zv[8];
        #pragma unroll
        for (int u2 = 0; u2 < 8; ++u2) zv[u2] = Z[(size_t)(i5+u2)*n + k];
        n0 += zv[0]*zv[0]; n1 += zv[1]*zv[1]; n2 += zv[2]*zv[2]; n3 += zv[3]*zv[3];
        n4 += zv[4]*zv[4]; n5 += zv[5]*zv[5]; n6 += zv[6]*zv[6]; n7 += zv[7]*zv[7];
    }
    double nrm = ((n0+n1)+(n2+n3)) + ((n4+n5)+(n6+n7));
    for (; i5 < n; ++i5){ double v = Z[(size_t)i5*n + k]; nrm += v*v; }
    double s = 1.0/sqrt(nrm);
    for (int i6 = 0; i6 + 8 <= n; i6 += 8){
        double zv[8];
        #pragma unroll
        for (int u2 = 0; u2 < 8; ++u2) zv[u2] = Z[(size_t)(i6+u2)*n + k];
        #pragma unroll
        for (int u2 = 0; u2 < 8; ++u2) Z[(size_t)(i6+u2)*n + k] = zv[u2]*s;
    }
}

// ============================ batched blocked-WY back-transform ============================
__global__ __launch_bounds__(256) void wy_buildV_k(const double* __restrict__ A64, const double* __restrict__ scaleg,
                                                   double* __restrict__ Vbig, int n)
{
    size_t idx = (size_t)blockIdx.x*256 + threadIdx.x;
    if (idx >= (size_t)NWY*1024*64) return;
    int g = (int)(idx >> 16);
    int r = (int)((idx >> 6) & 1023);
    int t = (int)(idx & 63);
    int b0 = g*64;
    int nbsz = (n - 2) - b0; if (nbsz > 64) nbsz = 64;
    double v = 0.0;
    if (t < nbsz){
        int j = b0 + t;
        if (r == j + 1) v = 1.0;
        else if (r > j + 1) v = A64[(size_t)j*n + r]*scaleg[j];
    }
    Vbig[idx] = v;
}

__global__ __launch_bounds__(256) void wy_buildT_k(const double* __restrict__ Vbig, const double* __restrict__ tau,
                                                   double* __restrict__ Tbig, int n)
{
    __shared__ double G[64][65];
    __shared__ double Ts[64][65];
    __shared__ double Vs[32][65];
    const int g = blockIdx.x;
    const int tid = threadIdx.x;
    const double* __restrict__ V = Vbig + ((size_t)g << 16);
    const int b0 = g*64;
    int nbsz = (n - 2) - b0; if (nbsz > 64) nbsz = 64;
    for (int p = tid; p < 64*64; p += 256) G[p >> 6][p & 63] = 0.0;
    __syncthreads();
    for (int rb = b0; rb < n; rb += 32){
        for (int s = tid; s < 2048; s += 256){
            int rr = s >> 6, tt = s & 63;
            Vs[rr][tt] = V[((size_t)(rb + rr) << 6) + tt];
        }
        __syncthreads();
        for (int p = tid; p < 4096; p += 256){
            int t = p >> 6, s2 = p & 63;
            if (t < s2 && s2 < nbsz){
                double acc = 0.0;
                #pragma unroll 8
                for (int rr = 0; rr < 32; ++rr) acc += Vs[rr][t]*Vs[rr][s2];
                G[t][s2] += acc;
            }
        }
        __syncthreads();
    }
    for (int t = nbsz - 1; t >= 0; --t){
        for (int u = tid; u < 64; u += 256){
            double val = 0.0;
            if (u == t) val = tau[b0 + t];
            else if (u > t && u < nbsz){
                double s = 0.0;
                for (int s2 = t + 1; s2 <= u; ++s2) s += G[t][s2]*Ts[s2][u];
                val = -tau[b0 + t]*s;
            }
            Ts[t][u] = val;
        }
        __syncthreads();
    }
    for (int p = tid; p < 64*64; p += 256){
        int t = p >> 6, u = p & 63;
        Tbig[((size_t)g << 12) + p] = (t < nbsz) ? Ts[t][u] : 0.0;
    }
}

// 1024-thread WY apply: 64-row chunks, one (t,c) pair per thread.
__global__ __launch_bounds__(1024) void wy_apply_k(const double* __restrict__ Vbig, const double* __restrict__ Tbig,
                                                   double* __restrict__ Z, int n)
{
    __shared__ double Vs[64][65];
    __shared__ double Zs[64][17];
    __shared__ double Y[64][17];
    __shared__ double W[64][17];
    const int tid = threadIdx.x;        // 0..1023
    const int c   = tid & 15;
    const int tq  = tid >> 4;           // 0..63
    const int c0  = blockIdx.x * 16;

    for (int g = NWY - 1; g >= 0; --g){
        const double* __restrict__ V = Vbig + ((size_t)g << 16);
        const double* __restrict__ T = Tbig + ((size_t)g << 12);
        const int b0 = g*64;
        double acc = 0.0;
        for (int rb = b0; rb < n; rb += 64){
            for (int s = tid; s < 4096; s += 1024){
                int rr = s >> 6, tt = s & 63;
                Vs[rr][tt] = V[((size_t)(rb + rr) << 6) + tt];
            }
            {
                int rr = tid >> 4, cc = tid & 15;
                Zs[rr][cc] = Z[(size_t)(rb + rr)*n + c0 + cc];
            }
            __syncthreads();
            #pragma unroll 8
            for (int rr = 0; rr < 64; ++rr)
                acc += Vs[rr][tq]*Zs[rr][c];
            __syncthreads();
        }
        Y[tq][c] = acc;
        __syncthreads();
        {
            double a = 0.0;
            for (int s = tq; s < 64; ++s) a += T[(tq << 6) + s]*Y[s][c];
            W[tq][c] = a;
        }
        __syncthreads();
        for (int rb = b0; rb < n; rb += 64){
            for (int s = tid; s < 4096; s += 1024){
                int rr = s >> 6, tt = s & 63;
                Vs[rr][tt] = V[((size_t)(rb + rr) << 6) + tt];
            }
            __syncthreads();
            {
                int rr = tid >> 4, cc = tid & 15;
                double s2 = 0.0;
                #pragma unroll 16
                for (int t = 0; t < 64; ++t) s2 += Vs[rr][t]*W[t][cc];
                Z[(size_t)(rb + rr)*n + c0 + cc] -= s2;
            }
            __syncthreads();
        }
        __syncthreads();
    }
}

// ============================ host dispatch helpers ============================
static void gemmf32(hipStream_t st, int epi,
                    const float* A, const float* B, float* C, int M, int N, int K,
                    const float* bias, const float* D)
{
    if ((K & 15) == 0 && (N & 7) == 0){
        if (M >= 768){
            dim3 g((N + 127)/128, (M + 127)/128), b(256);
            switch (epi){
            case EPI_NONE:      gemm128db<EPI_NONE><<<g, b, 0, st>>>(A, B, C, M, N, K, bias, D); break;
            case EPI_BIAS:      gemm128db<EPI_BIAS><<<g, b, 0, st>>>(A, B, C, M, N, K, bias, D); break;
            case EPI_BIAS_ADD:  gemm128db<EPI_BIAS_ADD><<<g, b, 0, st>>>(A, B, C, M, N, K, bias, D); break;
            case EPI_ABS_DIAG1: gemm128db<EPI_ABS_DIAG1><<<g, b, 0, st>>>(A, B, C, M, N, K, bias, D); break;
            case EPI_RELU:      gemm128db<EPI_RELU><<<g, b, 0, st>>>(A, B, C, M, N, K, bias, D); break;
            }
        } else {
            dim3 g((N + 127)/128, (M + 63)/64), b(128);
            switch (epi){
            case EPI_NONE:      gemm_db<EPI_NONE><<<g, b, 0, st>>>(A, B, C, M, N, K, bias, D); break;
            case EPI_BIAS:      gemm_db<EPI_BIAS><<<g, b, 0, st>>>(A, B, C, M, N, K, bias, D); break;
            case EPI_BIAS_ADD:  gemm_db<EPI_BIAS_ADD><<<g, b, 0, st>>>(A, B, C, M, N, K, bias, D); break;
            case EPI_ABS_DIAG1: gemm_db<EPI_ABS_DIAG1><<<g, b, 0, st>>>(A, B, C, M, N, K, bias, D); break;
            case EPI_RELU:      gemm_db<EPI_RELU><<<g, b, 0, st>>>(A, B, C, M, N, K, bias, D); break;
            }
        }
    } else {
        dim3 g((N + 63)/64, (M + 63)/64), b(256);
        switch (epi){
        case EPI_NONE:      gemm32<EPI_NONE><<<g, b, 0, st>>>(A, B, C, M, N, K, bias, D); break;
        case EPI_BIAS:      gemm32<EPI_BIAS><<<g, b, 0, st>>>(A, B, C, M, N, K, bias, D); break;
        case EPI_BIAS_ADD:  gemm32<EPI_BIAS_ADD><<<g, b, 0, st>>>(A, B, C, M, N, K, bias, D); break;
        case EPI_ABS_DIAG1: gemm32<EPI_ABS_DIAG1><<<g, b, 0, st>>>(A, B, C, M, N, K, bias, D); break;
        case EPI_RELU:      gemm32<EPI_RELU><<<g, b, 0, st>>>(A, B, C, M, N, K, bias, D); break;
        }
    }
}

// ============================ kernel_launch ============================
extern "C" void kernel_launch(void* const* d_in, const int* in_sizes, int n_in,
                              void* d_out, int out_size, void* d_ws, size_t ws_size,
                              hipStream_t stream)
{
    (void)in_sizes; (void)n_in; (void)out_size; (void)ws_size;
    const float* lr       = (const float*)d_in[0];
    const float* gsr_w    = (const float*)d_in[1];
    const float* start_w  = (const float*)d_in[2];
    const float* start_b  = (const float*)d_in[3];
    const float* down_w   = (const float*)d_in[4];
    const float* down_b   = (const float*)d_in[5];
    const float* pool_w   = (const float*)d_in[6];
    const float* pool_b   = (const float*)d_in[7];
    const float* bottom_w = (const float*)d_in[8];
    const float* bottom_b = (const float*)d_in[9];
    const float* end_w    = (const float*)d_in[10];
    const float* end_b    = (const float*)d_in[11];
    const float* up_w     = (const float*)d_in[12];
    const float* up_b     = (const float*)d_in[13];
    const float* gc1      = (const float*)d_in[14];
    const float* gc2      = (const float*)d_in[15];

    float* out_z     = (float*)d_out;                       // [2048,2048]
    float* out_net   = out_z + (size_t)HRD*HRD;             // [1024,2048]
    float* out_start = out_net + (size_t)NN*HRD;            // [1024,320]
    float* out_adj   = out_start + (size_t)NN*DIMF;         // [2048,2048]

    static const int LVL_N[4] = {1024, 921, 644, 386};
    static const int LVL_K[4] = {921, 644, 386, 193};

    // -------- workspace arena --------
    char* Wb = (char*)d_ws;
    size_t off = 0;
    auto alloc = [&](size_t bb)->char*{ char* p = Wb + off; off = (off + bb + 255) & ~(size_t)255; return p; };

    float*  A32  = (float*) alloc((size_t)NN*NN*4);
    double* A64  = (double*)alloc((size_t)NN*NN*8);
    float*  UfT  = (float*) alloc((size_t)NN*NN*4);   // U^T as [k][j] fp32
    double* r64  = (double*)alloc(NN*8);
    double* dD   = (double*)alloc(NN*8);
    double* dE   = (double*)alloc(NN*8);
    double* dTau = (double*)alloc(NN*8);
    double* dScl = (double*)alloc(NN*8);
    double* dWev = (double*)alloc(NN*8);
    double* pvA  = (double*)alloc(NN*8);              // kept (init target), unused by coop11
    double* Rst  = (double*)alloc((size_t)2*NN*8);    // double-buffered pivot-row stage (sc1)
    unsigned* barcnt = (unsigned*)alloc(8192);
    char* SBASE = Wb + off;

    // P2 overlay (U-Net)
    size_t so = 0;
    auto salloc = [&](size_t bb)->char*{ char* p = SBASE + so; so = (so + bb + 255) & ~(size_t)255; return p; };
    float* XT  = (float*)salloc((size_t)NN*DIMF*4);
    float* XP1 = (float*)salloc((size_t)NN*DIMF*4);
    float* XP2 = (float*)salloc((size_t)NN*DIMF*4);
    float* XU  = (float*)salloc((size_t)NN*DIMF*4);
    float* DN[4]; for (int l = 0; l < 4; ++l) DN[l] = (float*)salloc((size_t)NN*DIMF*4);
    float* Asub[4];
    for (int l = 0; l < 4; ++l) Asub[l] = (float*)salloc((size_t)LVL_K[l]*LVL_K[l]*4);
    float* SC = (float*)salloc(NN*4);
    int*   IDX[4]; for (int l = 0; l < 4; ++l) IDX[l] = (int*)salloc(NN*4);
    float* VAL[4]; for (int l = 0; l < 4; ++l) VAL[l] = (float*)salloc(NN*4);
    float* XC  = (float*)salloc((size_t)NN*2*DIMF*4);
    float* AXC = (float*)salloc((size_t)NN*2*DIMF*4);

    // P3 overlay (eigensolver scratch)
    const size_t PL = (size_t)NN*NN*8;
    double* Z64 = (double*)(SBASE);
    double* FD  = (double*)(SBASE + PL);       // doubles as Pmat during sytrd, Vbig during WY
    double* FL  = (double*)(SBASE + 2*PL);     // doubles as Tbig during WY
    double* FU  = (double*)(SBASE + 3*PL);
    double* FU2 = (double*)(SBASE + 4*PL);
    signed char* FPIV = (signed char*)(SBASE + 5*PL);
    double* Pmat = FD;
    double* Vbig = FD;
    double* Tbig = FL;

    // P4 overlay (GSR / refinement)
    const size_t MB8  = (size_t)HRD*NN*4;    // 8 MiB
    const size_t MB16 = (size_t)HRD*HRD*4;   // 16 MiB
    float* P4a   = (float*)(SBASE);
    float* P4t1  = (float*)(SBASE + MB8);
    float* P4adT = (float*)(SBASE);
    float* P4Zb  = (float*)(SBASE + MB16);
    float* P4ZG  = (float*)(SBASE);
    float* P4h1  = (float*)(SBASE + MB8);
    float* P4HG  = (float*)(SBASE + MB16);
    float* P4h2  = (float*)(SBASE);

    // =============== P1: normalized adjacency ===============
    rowsum_rsqrt_k<<<NN, 256, 0, stream>>>(lr, r64, NN);
    build_A_k<<<(NN*NN + 255)/256, 256, 0, stream>>>(lr, r64, A32, A64, NN);

    // =============== P2: graph U-Net (fp32) ===============
    gemmf32(stream, EPI_BIAS, A32, start_w, out_start, NN, DIMF, NN, start_b, nullptr);

    const float* Xcur = out_start;
    const float* Acur = A32;
    float* ping = XP1; float* pong = XP2;
    for (int l = 0; l < 4; ++l){
        int nl = LVL_N[l], kl = LVL_K[l];
        gemmf32(stream, EPI_NONE, Acur, Xcur, XT, nl, DIMF, nl, nullptr, nullptr);
        gemmf32(stream, EPI_BIAS, XT, down_w + (size_t)l*DIMF*DIMF, DN[l], nl, DIMF, DIMF,
                down_b + (size_t)l*DIMF, nullptr);
        score_k<<<(nl + 3)/4, 256, 0, stream>>>(DN[l], pool_w + (size_t)l*DIMF, pool_b + l, SC, nl, DIMF);
        topk_k<<<1, 256, 0, stream>>>(SC, nl, kl, IDX[l], VAL[l]);
        gatherX_k<<<(unsigned)(((size_t)kl*DIMF + 255)/256), 256, 0, stream>>>(DN[l], IDX[l], VAL[l], ping, kl, DIMF);
        gatherA_k<<<(unsigned)(((size_t)kl*kl + 255)/256), 256, 0, stream>>>(Acur, IDX[l], Asub[l], kl, nl);
        Xcur = ping; Acur = Asub[l];
        float* t = ping; ping = pong; pong = t;
    }
    gemmf32(stream, EPI_NONE, Acur, Xcur, XT, 193, DIMF, 193, nullptr, nullptr);
    float* Xb = ping;
    gemmf32(stream, EPI_BIAS, XT, bottom_w, Xb, 193, DIMF, DIMF, bottom_b, nullptr);
    const float* Xup = Xb;
    float* upbuf[2] = { (Xb == XP1) ? XP2 : XP1, (Xb == XP1) ? XP1 : XP2 };
    for (int i2 = 0; i2 < 4; ++i2){
        int jl = 3 - i2;
        int nj = LVL_N[jl];
        int kj = LVL_K[jl];
        fill0_k<<<(unsigned)(((size_t)nj*DIMF + 255)/256), 256, 0, stream>>>(XU, (size_t)nj*DIMF);
        scatterX_k<<<(unsigned)(((size_t)kj*DIMF + 255)/256), 256, 0, stream>>>(Xup, IDX[jl], XU, kj, DIMF);
        const float* Aj = (jl == 0) ? A32 : Asub[jl - 1];
        gemmf32(stream, EPI_NONE, Aj, XU, XT, nj, DIMF, nj, nullptr, nullptr);
        float* Xn = upbuf[i2 & 1];
        gemmf32(stream, EPI_BIAS_ADD, XT, up_w + (size_t)i2*DIMF*DIMF, Xn, nj, DIMF, DIMF,
                up_b + (size_t)i2*DIMF, DN[jl]);
        Xup = Xn;
    }
    concat_k<<<(unsigned)(((size_t)NN*2*DIMF + 255)/256), 256, 0, stream>>>(Xup, out_start, XC, NN, DIMF);
    gemmf32(stream, EPI_NONE, A32, XC, AXC, NN, 2*DIMF, NN, nullptr, nullptr);
    gemmf32(stream, EPI_BIAS, AXC, end_w, out_net, NN, HRD, 2*DIMF, end_b, nullptr);

    // =============== P3: eigendecomposition of A (fp64) ===============
    const int JEND = NN - TB;
    init_sytrd_k<<<4, 256, 0, stream>>>(pvA, barcnt, NN);
    filld0_k<<<(unsigned)(((size_t)JEND*NN + 255)/256), 256, 0, stream>>>(Pmat, (size_t)JEND*NN);
    sytrd_coop11<<<CB3, BT3, 0, stream>>>(A64, dE, dTau, dScl, Pmat, Rst, barcnt, NN, JEND);
    hh_tail<<<1, 256, 0, stream>>>(A64, dE, dTau, dScl, NN);
    extract_de_k<<<4, 256, 0, stream>>>(A64, dD, dE, NN);
    bisect_k<<<4, 256, 0, stream>>>(dD, dE, dWev, NN);
    invit_k<<<4, 256, 0, stream>>>(dD, dE, dWev, FD, FL, FU, FU2, FPIV, Z64, NN);
    wy_buildV_k<<<(unsigned)(((size_t)NWY*1024*64 + 255)/256), 256, 0, stream>>>(A64, dScl, Vbig, NN);
    wy_buildT_k<<<NWY, 256, 0, stream>>>(Vbig, dTau, Tbig, NN);
    wy_apply_k<<<NN/16, 1024, 0, stream>>>(Vbig, Tbig, Z64, NN);
    {
        dim3 g(NN/32, NN/32), b(256);
        transpose_cast_k<<<g, b, 0, stream>>>(Z64, UfT, NN);
    }

    // =============== P4: GSR layer + refinement (fp32) ===============
    build_a_k<<<(unsigned)(((size_t)HRD*NN + 255)/256), 256, 0, stream>>>(gsr_w, P4a);
    gemmf32(stream, EPI_NONE, P4a, UfT, P4t1, HRD, NN, NN, nullptr, nullptr);               // a @ U^T
    gemmf32(stream, EPI_ABS_DIAG1, P4t1, out_net, out_adj, HRD, HRD, NN, nullptr, nullptr); // adj
    {
        dim3 g(HRD/32, HRD/32), b(256);
        transpose32_k<<<g, b, 0, stream>>>(out_adj, P4adT, HRD);                            // adj^T
    }
    {
        const int T = HRD >> 7;                       // 16 tiles -> 136 upper pairs
        gemm_symAAT<<<T*(T+1)/2, 256, 0, stream>>>(out_adj, P4adT, P4Zb, HRD);              // adj @ adj^T (sym)
    }
    symabs1_k<<<(unsigned)(((size_t)HRD*HRD + 255)/256), 256, 0, stream>>>(P4Zb, HRD);      // Z
    gemmf32(stream, EPI_NONE, P4Zb, gc1, P4ZG, HRD, NN, HRD, nullptr, nullptr);             // Z @ gc1
    gemmf32(stream, EPI_RELU, out_adj, P4ZG, P4h1, HRD, NN, HRD, nullptr, nullptr);         // h1
    gemmf32(stream, EPI_NONE, P4h1, gc2, P4HG, HRD, HRD, NN, nullptr, nullptr);             // h1 @ gc2
    gemmf32(stream, EPI_RELU, out_adj, P4HG, P4h2, HRD, HRD, HRD, nullptr, nullptr);        // h2
    final_z_k<<<(unsigned)(((size_t)HRD*HRD + 255)/256), 256, 0, stream>>>(P4h2, out_z, HRD); // z
}

// Round 9
// 18064.397 us; speedup vs baseline: 1.0679x; 1.0679x over previous
//
#include <hip/hip_runtime.h>
#include <cstddef>
#include <cstdint>
#include <math.h>

// ============================ constants ============================
static constexpr int NN   = 1024;   // lr_dim
static constexpr int HRD  = 2048;   // hr_dim
static constexpr int DIMF = 320;
static constexpr int TB   = 85;     // sytrd LDS tail block
static constexpr int CB3  = 128;    // persistent sytrd blocks (8 rows each)
static constexpr int BT3  = 1024;   // threads per sytrd block (16 waves)
static constexpr int NWY  = 16;     // WY reflector groups (64 each)

#define EPI_NONE      0
#define EPI_BIAS      1
#define EPI_BIAS_ADD  2
#define EPI_ABS_DIAG1 3
#define EPI_RELU      4

// agent-scope coherent access helpers (sc1).
__device__ __forceinline__ double gload(const double* p){
    return __hip_atomic_load(p, __ATOMIC_RELAXED, __HIP_MEMORY_SCOPE_AGENT);
}
__device__ __forceinline__ void gstore(double* p, double v){
    __hip_atomic_store(p, v, __ATOMIC_RELAXED, __HIP_MEMORY_SCOPE_AGENT);
}

// ============================ fp32 GEMM 64-tile (fallback, odd K) ============================
template<int EPI>
__global__ __launch_bounds__(256) void gemm32(
    const float* __restrict__ A, const float* __restrict__ B, float* __restrict__ C,
    int M, int N, int K, const float* __restrict__ bias, const float* __restrict__ D)
{
    __shared__ float As[16][65];
    __shared__ float Bs[16][65];
    const int bm = blockIdx.y << 6, bn = blockIdx.x << 6;
    const int tid = threadIdx.x;
    const int tm = (tid >> 4) << 2, tn = (tid & 15) << 2;
    float acc[4][4] = {};
    const int kt = (K + 15) >> 4;
    for (int k0 = 0; k0 < kt; ++k0){
        const int kb = k0 << 4;
        for (int t = tid; t < 1024; t += 256){
            int m = t >> 4, k = t & 15;
            int gm = bm + m, gk = kb + k;
            As[k][m] = (gm < M && gk < K) ? A[(size_t)gm*K + gk] : 0.f;
        }
        for (int t = tid; t < 1024; t += 256){
            int k = t >> 6, nn2 = t & 63;
            int gk = kb + k, gn = bn + nn2;
            Bs[k][nn2] = (gk < K && gn < N) ? B[(size_t)gk*N + gn] : 0.f;
        }
        __syncthreads();
        #pragma unroll
        for (int k = 0; k < 16; ++k){
            float a0 = As[k][tm], a1 = As[k][tm+1], a2 = As[k][tm+2], a3 = As[k][tm+3];
            float b0 = Bs[k][tn], b1 = Bs[k][tn+1], b2 = Bs[k][tn+2], b3 = Bs[k][tn+3];
            acc[0][0] += a0*b0; acc[0][1] += a0*b1; acc[0][2] += a0*b2; acc[0][3] += a0*b3;
            acc[1][0] += a1*b0; acc[1][1] += a1*b1; acc[1][2] += a1*b2; acc[1][3] += a1*b3;
            acc[2][0] += a2*b0; acc[2][1] += a2*b1; acc[2][2] += a2*b2; acc[2][3] += a2*b3;
            acc[3][0] += a3*b0; acc[3][1] += a3*b1; acc[3][2] += a3*b2; acc[3][3] += a3*b3;
        }
        __syncthreads();
    }
    #pragma unroll
    for (int r = 0; r < 4; ++r){
        int gm = bm + tm + r; if (gm >= M) continue;
        #pragma unroll
        for (int c = 0; c < 4; ++c){
            int gn = bn + tn + c; if (gn >= N) continue;
            float v = acc[r][c];
            if (EPI == EPI_BIAS)            v += bias[gn];
            else if (EPI == EPI_BIAS_ADD)   v += bias[gn] + D[(size_t)gm*N + gn];
            else if (EPI == EPI_ABS_DIAG1)  v = (gm == gn) ? 1.0f : fabsf(v);
            else if (EPI == EPI_RELU)       v = fmaxf(v, 0.0f);
            C[(size_t)gm*N + gn] = v;
        }
    }
}

// ============================ fp32 GEMM 64x128 double-buffered (K%16==0, N%8==0) ============================
template<int EPI>
__global__ __launch_bounds__(128) void gemm_db(
    const float* __restrict__ A, const float* __restrict__ B, float* __restrict__ C,
    int M, int N, int K, const float* __restrict__ bias, const float* __restrict__ D)
{
    __shared__ float As[2][16][68];
    __shared__ float Bs[2][16][132];
    const int bm = blockIdx.y << 6;
    const int bn = blockIdx.x << 7;
    const int tid = threadIdx.x;
    const int tm = (tid >> 4) << 3;
    const int tn = (tid & 15) << 3;
    const int ar = tid >> 2;
    const int af = tid & 3;
    const int br = tid >> 5;
    const int bf = tid & 31;

    float4 a_reg[2], b_reg[4];

    auto loadA = [&](int kb, int q) -> float4 {
        int gm = bm + ar + (q << 5);
        int gk = kb + (af << 2);
        if (gm < M) return *(const float4*)(A + (size_t)gm*K + gk);
        return make_float4(0.f,0.f,0.f,0.f);
    };
    auto loadB = [&](int kb, int q) -> float4 {
        int gk = kb + br + (q << 2);
        int gn = bn + (bf << 2);
        if (gn < N) return *(const float4*)(B + (size_t)gk*N + gn);
        return make_float4(0.f,0.f,0.f,0.f);
    };
    auto stash = [&](int p){
        #pragma unroll
        for (int q = 0; q < 2; ++q){
            int r = ar + (q << 5);
            As[p][(af<<2)+0][r] = a_reg[q].x; As[p][(af<<2)+1][r] = a_reg[q].y;
            As[p][(af<<2)+2][r] = a_reg[q].z; As[p][(af<<2)+3][r] = a_reg[q].w;
        }
        #pragma unroll
        for (int q = 0; q < 4; ++q)
            *(float4*)&Bs[p][br + (q<<2)][bf << 2] = b_reg[q];
    };

    #pragma unroll
    for (int q = 0; q < 2; ++q) a_reg[q] = loadA(0, q);
    #pragma unroll
    for (int q = 0; q < 4; ++q) b_reg[q] = loadB(0, q);
    stash(0);
    __syncthreads();

    float acc[8][8] = {};
    int p = 0;
    for (int kb = 16; ; kb += 16){
        const bool more = (kb < K);
        if (more){
            #pragma unroll
            for (int q = 0; q < 2; ++q) a_reg[q] = loadA(kb, q);
            #pragma unroll
            for (int q = 0; q < 4; ++q) b_reg[q] = loadB(kb, q);
        }
        #pragma unroll
        for (int k = 0; k < 16; ++k){
            float4 a0 = *(const float4*)&As[p][k][tm];
            float4 a1 = *(const float4*)&As[p][k][tm+4];
            float4 b0 = *(const float4*)&Bs[p][k][tn];
            float4 b1 = *(const float4*)&Bs[p][k][tn+4];
            float av[8] = {a0.x,a0.y,a0.z,a0.w,a1.x,a1.y,a1.z,a1.w};
            float bv[8] = {b0.x,b0.y,b0.z,b0.w,b1.x,b1.y,b1.z,b1.w};
            #pragma unroll
            for (int i = 0; i < 8; ++i)
                #pragma unroll
                for (int jj = 0; jj < 8; ++jj) acc[i][jj] += av[i]*bv[jj];
        }
        if (!more) break;
        stash(p ^ 1);
        __syncthreads();
        p ^= 1;
    }
    #pragma unroll
    for (int i = 0; i < 8; ++i){
        int gm = bm + tm + i; if (gm >= M) continue;
        #pragma unroll
        for (int jj = 0; jj < 8; ++jj){
            int gn = bn + tn + jj; if (gn >= N) continue;
            float v = acc[i][jj];
            if (EPI == EPI_BIAS)            v += bias[gn];
            else if (EPI == EPI_BIAS_ADD)   v += bias[gn] + D[(size_t)gm*N + gn];
            else if (EPI == EPI_ABS_DIAG1)  v = (gm == gn) ? 1.0f : fabsf(v);
            else if (EPI == EPI_RELU)       v = fmaxf(v, 0.0f);
            C[(size_t)gm*N + gn] = v;
        }
    }
}

// ============================ fp32 GEMM 128x128 double-buffered (K%16==0, N%8==0, big M) ============================
template<int EPI>
__global__ __launch_bounds__(256) void gemm128db(
    const float* __restrict__ A, const float* __restrict__ B, float* __restrict__ C,
    int M, int N, int K, const float* __restrict__ bias, const float* __restrict__ D)
{
    __shared__ float As[2][16][132];
    __shared__ float Bs[2][16][132];
    const int bm = blockIdx.y << 7, bn = blockIdx.x << 7;
    const int tid = threadIdx.x;
    const int tm = (tid >> 4) << 3;
    const int tn = (tid & 15) << 3;
    const int ar = tid >> 1;         // 0..127
    const int ak = (tid & 1) << 3;   // 0/8
    const int br = tid >> 4;         // 0..15
    const int bc = (tid & 15) << 3;  // 0..120

    float4 a0r, a1r, b0r, b1r;

    auto loadA = [&](int kb){
        int gm = bm + ar, gk = kb + ak;
        if (gm < M){
            const float* p = A + (size_t)gm*K + gk;
            a0r = *(const float4*)p; a1r = *(const float4*)(p + 4);
        } else { a0r = make_float4(0.f,0.f,0.f,0.f); a1r = a0r; }
    };
    auto loadB = [&](int kb){
        int gk = kb + br, gn = bn + bc;
        if (gn + 7 < N){
            const float* p = B + (size_t)gk*N + gn;
            b0r = *(const float4*)p; b1r = *(const float4*)(p + 4);
        } else {
            float t0[8];
            #pragma unroll
            for (int i = 0; i < 8; ++i){ int g2 = gn + i; t0[i] = (g2 < N) ? B[(size_t)gk*N + g2] : 0.f; }
            b0r = make_float4(t0[0],t0[1],t0[2],t0[3]); b1r = make_float4(t0[4],t0[5],t0[6],t0[7]);
        }
    };
    auto stash = [&](int p){
        As[p][ak+0][ar]=a0r.x; As[p][ak+1][ar]=a0r.y; As[p][ak+2][ar]=a0r.z; As[p][ak+3][ar]=a0r.w;
        As[p][ak+4][ar]=a1r.x; As[p][ak+5][ar]=a1r.y; As[p][ak+6][ar]=a1r.z; As[p][ak+7][ar]=a1r.w;
        *(float4*)&Bs[p][br][bc] = b0r; *(float4*)&Bs[p][br][bc+4] = b1r;
    };

    loadA(0); loadB(0); stash(0);
    __syncthreads();

    float acc[8][8] = {};
    int p = 0;
    for (int kb = 16; ; kb += 16){
        const bool more = (kb < K);
        if (more){ loadA(kb); loadB(kb); }
        #pragma unroll
        for (int k = 0; k < 16; ++k){
            float4 a0 = *(const float4*)&As[p][k][tm];
            float4 a1 = *(const float4*)&As[p][k][tm+4];
            float4 b0 = *(const float4*)&Bs[p][k][tn];
            float4 b1 = *(const float4*)&Bs[p][k][tn+4];
            float av[8] = {a0.x,a0.y,a0.z,a0.w,a1.x,a1.y,a1.z,a1.w};
            float bv[8] = {b0.x,b0.y,b0.z,b0.w,b1.x,b1.y,b1.z,b1.w};
            #pragma unroll
            for (int i = 0; i < 8; ++i)
                #pragma unroll
                for (int jj = 0; jj < 8; ++jj) acc[i][jj] += av[i]*bv[jj];
        }
        if (!more) break;
        stash(p ^ 1);
        __syncthreads();
        p ^= 1;
    }
    #pragma unroll
    for (int i = 0; i < 8; ++i){
        int gm = bm + tm + i; if (gm >= M) continue;
        #pragma unroll
        for (int jj = 0; jj < 8; ++jj){
            int gn = bn + tn + jj; if (gn >= N) continue;
            float v = acc[i][jj];
            if (EPI == EPI_BIAS)            v += bias[gn];
            else if (EPI == EPI_BIAS_ADD)   v += bias[gn] + D[(size_t)gm*N + gn];
            else if (EPI == EPI_ABS_DIAG1)  v = (gm == gn) ? 1.0f : fabsf(v);
            else if (EPI == EPI_RELU)       v = fmaxf(v, 0.0f);
            C[(size_t)gm*N + gn] = v;
        }
    }
}

// ============================ symmetric C = A @ A^T (B = A^T given), n%128==0 ============================
__global__ __launch_bounds__(256) void gemm_symAAT(
    const float* __restrict__ A, const float* __restrict__ Bt, float* __restrict__ C, int n)
{
    __shared__ float As[2][16][132];
    __shared__ float Bs[2][16][132];
    const int T = n >> 7;
    int ti = 0, rem = blockIdx.x;
    while (rem >= T - ti){ rem -= T - ti; ++ti; }
    const int tj = ti + rem;
    const int bm = ti << 7, bn = tj << 7;
    const int tid = threadIdx.x;
    const int tm = (tid >> 4) << 3;
    const int tn = (tid & 15) << 3;
    const int ar = tid >> 1;
    const int ak = (tid & 1) << 3;
    const int br = tid >> 4;
    const int bc = (tid & 15) << 3;

    float4 a0r, a1r, b0r, b1r;
    auto loadA = [&](int kb){
        const float* p = A + (size_t)(bm + ar)*n + kb + ak;
        a0r = *(const float4*)p; a1r = *(const float4*)(p + 4);
    };
    auto loadB = [&](int kb){
        const float* p = Bt + (size_t)(kb + br)*n + bn + bc;
        b0r = *(const float4*)p; b1r = *(const float4*)(p + 4);
    };
    auto stash = [&](int p){
        As[p][ak+0][ar]=a0r.x; As[p][ak+1][ar]=a0r.y; As[p][ak+2][ar]=a0r.z; As[p][ak+3][ar]=a0r.w;
        As[p][ak+4][ar]=a1r.x; As[p][ak+5][ar]=a1r.y; As[p][ak+6][ar]=a1r.z; As[p][ak+7][ar]=a1r.w;
        *(float4*)&Bs[p][br][bc] = b0r; *(float4*)&Bs[p][br][bc+4] = b1r;
    };

    loadA(0); loadB(0); stash(0);
    __syncthreads();

    float acc[8][8] = {};
    int p = 0;
    for (int kb = 16; ; kb += 16){
        const bool more = (kb < n);
        if (more){ loadA(kb); loadB(kb); }
        #pragma unroll
        for (int k = 0; k < 16; ++k){
            float4 a0 = *(const float4*)&As[p][k][tm];
            float4 a1 = *(const float4*)&As[p][k][tm+4];
            float4 b0 = *(const float4*)&Bs[p][k][tn];
            float4 b1 = *(const float4*)&Bs[p][k][tn+4];
            float av[8] = {a0.x,a0.y,a0.z,a0.w,a1.x,a1.y,a1.z,a1.w};
            float bv[8] = {b0.x,b0.y,b0.z,b0.w,b1.x,b1.y,b1.z,b1.w};
            #pragma unroll
            for (int i = 0; i < 8; ++i)
                #pragma unroll
                for (int jj = 0; jj < 8; ++jj) acc[i][jj] += av[i]*bv[jj];
        }
        if (!more) break;
        stash(p ^ 1);
        __syncthreads();
        p ^= 1;
    }
    #pragma unroll
    for (int i = 0; i < 8; ++i){
        #pragma unroll
        for (int jj = 0; jj < 8; ++jj)
            C[(size_t)(bm + tm + i)*n + (bn + tn + jj)] = acc[i][jj];
    }
    if (ti != tj){
        #pragma unroll
        for (int i = 0; i < 8; ++i)
            #pragma unroll
            for (int jj = 0; jj < 8; ++jj)
                C[(size_t)(bn + tn + jj)*n + (bm + tm + i)] = acc[i][jj];
    }
}

// ============================ small kernels ============================
__global__ __launch_bounds__(256) void rowsum_rsqrt_k(const float* __restrict__ lr, double* __restrict__ r64, int n)
{
    __shared__ double sm[256];
    int row = blockIdx.x;
    double s = 0.0;
    for (int j = threadIdx.x; j < n; j += 256) s += (double)lr[(size_t)row*n + j];
    sm[threadIdx.x] = s; __syncthreads();
    for (int o = 128; o; o >>= 1){ if (threadIdx.x < o) sm[threadIdx.x] += sm[threadIdx.x + o]; __syncthreads(); }
    if (threadIdx.x == 0){
        double t = sm[0];
        r64[row] = (t > 0.0) ? 1.0/sqrt(t) : 0.0;
    }
}

__global__ __launch_bounds__(256) void build_A_k(const float* __restrict__ lr, const double* __restrict__ r64,
                                                 float* __restrict__ A32, double* __restrict__ A64, int n)
{
    size_t idx = (size_t)blockIdx.x*256 + threadIdx.x;
    if (idx >= (size_t)n*n) return;
    int i = (int)(idx / n), j = (int)(idx % n);
    if (j < i) return;
    double v = (double)lr[(size_t)j*n + i] * r64[i] * r64[j];
    A64[(size_t)i*n + j] = v; A64[(size_t)j*n + i] = v;
    float vf = (float)v;
    A32[(size_t)i*n + j] = vf; A32[(size_t)j*n + i] = vf;
}

__global__ __launch_bounds__(256) void score_k(const float* __restrict__ X, const float* __restrict__ pw,
                                               const float* __restrict__ pb, float* __restrict__ out,
                                               int n, int dim)
{
    int row = blockIdx.x*4 + (threadIdx.x >> 6);
    int lane = threadIdx.x & 63;
    if (row >= n) return;
    float acc = 0.f;
    for (int c = lane; c < dim; c += 64) acc += X[(size_t)row*dim + c]*pw[c];
    #pragma unroll
    for (int o = 32; o; o >>= 1) acc += __shfl_down(acc, o);
    if (lane == 0){
        float t = (acc + pb[0]) * 0.01f;
        out[row] = 1.0f/(1.0f + expf(-t));
    }
}

// jax.lax.top_k semantics: descending value, ties -> lower index first
__global__ __launch_bounds__(256) void topk_k(const float* __restrict__ scores, int n, int k,
                                              int* __restrict__ idxo, float* __restrict__ valo)
{
    __shared__ float s[1024];
    int tid = threadIdx.x;
    for (int i = tid; i < n; i += 256) s[i] = scores[i];
    __syncthreads();
    for (int i = tid; i < n; i += 256){
        float si = s[i]; int r = 0;
        for (int j = 0; j < n; ++j){
            float sj = s[j];
            r += (sj > si) || (sj == si && j < i);
        }
        if (r < k){ idxo[r] = i; valo[r] = si; }
    }
}

__global__ __launch_bounds__(256) void gatherX_k(const float* __restrict__ X, const int* __restrict__ idx,
                                                 const float* __restrict__ vals, float* __restrict__ Xo,
                                                 int k, int dim)
{
    size_t t = (size_t)blockIdx.x*256 + threadIdx.x;
    if (t >= (size_t)k*dim) return;
    int m = (int)(t / dim), c = (int)(t % dim);
    Xo[t] = X[(size_t)idx[m]*dim + c] * vals[m];
}

__global__ __launch_bounds__(256) void scatterX_k(const float* __restrict__ Xs, const int* __restrict__ idx,
                                                  float* __restrict__ Xu, int k, int dim)
{
    size_t t = (size_t)blockIdx.x*256 + threadIdx.x;
    if (t >= (size_t)k*dim) return;
    int m = (int)(t / dim), c = (int)(t % dim);
    Xu[(size_t)idx[m]*dim + c] = Xs[t];
}

__global__ __launch_bounds__(256) void gatherA_k(const float* __restrict__ A, const int* __restrict__ idx,
                                                 float* __restrict__ Ao, int k, int n)
{
    size_t t = (size_t)blockIdx.x*256 + threadIdx.x;
    if (t >= (size_t)k*k) return;
    int m1 = (int)(t / k), m2 = (int)(t % k);
    Ao[t] = A[(size_t)idx[m1]*n + idx[m2]];
}

__global__ __launch_bounds__(256) void fill0_k(float* __restrict__ p, size_t cnt)
{
    size_t t = (size_t)blockIdx.x*256 + threadIdx.x;
    if (t < cnt) p[t] = 0.f;
}

__global__ __launch_bounds__(256) void filld0_k(double* __restrict__ p, size_t cnt)
{
    size_t t = (size_t)blockIdx.x*256 + threadIdx.x;
    if (t < cnt) p[t] = 0.0;
}

__global__ __launch_bounds__(256) void init_sytrd_k(double* __restrict__ pv, unsigned* __restrict__ bar, int n)
{
    int t = blockIdx.x*256 + threadIdx.x;
    if (t < n) pv[t] = 0.0;
    if (t < 1024) bar[t] = 0u;
}

__global__ __launch_bounds__(256) void concat_k(const float* __restrict__ X, const float* __restrict__ orgX,
                                                float* __restrict__ Xc, int n, int dim)
{
    size_t t = (size_t)blockIdx.x*256 + threadIdx.x;
    size_t tot = (size_t)n*2*dim;
    if (t >= tot) return;
    int i = (int)(t / (2*dim)), c = (int)(t % (2*dim));
    Xc[t] = (c < dim) ? X[(size_t)i*dim + c] : orgX[(size_t)i*dim + (c - dim)];
}

__global__ __launch_bounds__(256) void build_a_k(const float* __restrict__ gsr, float* __restrict__ a)
{
    size_t idx = (size_t)blockIdx.x*256 + threadIdx.x;
    if (idx >= (size_t)HRD*NN) return;
    int i = (int)(idx >> 10), k = (int)(idx & 1023);
    a[idx] = gsr[(size_t)i*HRD + k] + gsr[(size_t)i*HRD + NN + k];
}

__global__ __launch_bounds__(256) void symabs1_k(float* __restrict__ Z, int n)
{
    size_t idx = (size_t)blockIdx.x*256 + threadIdx.x;
    if (idx >= (size_t)n*n) return;
    int i = (int)(idx / n), j = (int)(idx % n);
    if (i > j) return;
    float a = Z[(size_t)i*n + j], b = Z[(size_t)j*n + i];
    float v = 0.5f*(a + b);
    float o = (i == j) ? 1.0f : fabsf(v);
    Z[(size_t)i*n + j] = o; Z[(size_t)j*n + i] = o;
}

__global__ __launch_bounds__(256) void final_z_k(const float* __restrict__ h2, float* __restrict__ z, int n)
{
    size_t idx = (size_t)blockIdx.x*256 + threadIdx.x;
    if (idx >= (size_t)n*n) return;
    int i = (int)(idx / n), j = (int)(idx % n);
    if (i > j) return;
    float v = 0.5f*(h2[(size_t)i*n + j] + h2[(size_t)j*n + i]);
    float o = (i == j) ? 1.0f : fabsf(v);
    z[(size_t)i*n + j] = o; z[(size_t)j*n + i] = o;
}

// dst[c][r] = (float)src[r][c]   (n x n, n % 32 == 0)
__global__ __launch_bounds__(256) void transpose_cast_k(const double* __restrict__ src, float* __restrict__ dst, int n)
{
    __shared__ float tile[32][33];
    int r0 = blockIdx.y*32, c0 = blockIdx.x*32;
    int tx = threadIdx.x & 31, ty = threadIdx.x >> 5;
    for (int i = ty; i < 32; i += 8)
        tile[i][tx] = (float)src[(size_t)(r0 + i)*n + (c0 + tx)];
    __syncthreads();
    for (int i = ty; i < 32; i += 8)
        dst[(size_t)(c0 + i)*n + (r0 + tx)] = tile[tx][i];
}

// dst[c][r] = src[r][c]  (n x n, n % 32 == 0)
__global__ __launch_bounds__(256) void transpose32_k(const float* __restrict__ src, float* __restrict__ dst, int n)
{
    __shared__ float tile[32][33];
    int r0 = blockIdx.y*32, c0 = blockIdx.x*32;
    int tx = threadIdx.x & 31, ty = threadIdx.x >> 5;
    for (int i = ty; i < 32; i += 8)
        tile[i][tx] = src[(size_t)(r0 + i)*n + (c0 + tx)];
    __syncthreads();
    for (int i = ty; i < 32; i += 8)
        dst[(size_t)(c0 + i)*n + (r0 + tx)] = tile[tx][i];
}

// ============================ persistent Householder tridiagonalization ============================
// sytrd_coop8 (PROVEN BEST, round-5: 5.84 ms): fixed row ownership (block bid owns rows
// [8bid,8bid+8)), fused phase-A+pivot with one sc1 round, 2-round reduction, TREE barrier
// (per-group counters -> central), tid0-only arrival+spin, block-wide release sync, dynamic
// retirement, register-prefetch of the owned trailing-row slots overlapping phase A.
// Round 6-8 A/B/C: merged 1-round reduction (+1.2 ms) and flat barrier (+1.5 ms) both
// REGRESS; per-wave spin deadlocked. This structure is the empirical optimum.
__global__ __launch_bounds__(BT3) void sytrd_coop8(
    double* __restrict__ A, double* __restrict__ e, double* __restrict__ tauA,
    double* __restrict__ sclA, double* __restrict__ P,
    double* __restrict__ Rst, unsigned* __restrict__ bar, int n, int jend)
{
    __shared__ double VP[1024], WP[1024], VJ2[2][1024];
    __shared__ double redA[16], redB[16];
    const int tid   = threadIdx.x;
    const int bid   = blockIdx.x;
    const int lane  = tid & 63;
    const int wid   = tid >> 6;
    const int rwav  = wid >> 1;
    const int half  = wid & 1;
    const int u     = (bid << 3) + rwav;
    const int g     = bid >> 4;
    const int mylast = (bid << 3) + 7;
    const int cbase = half*64 + lane;

    double tau_p = 0.0, sc_p = 0.0;
    unsigned cumG = 0, cumC = 0;

    for (int j = 0; j < jend; ++j){
        const int m = n - 1 - j;
        double* __restrict__ VJnew = VJ2[j & 1];
        const double* __restrict__ VJold = VJ2[(j & 1) ^ 1];

        {
            const int retired = j >> 3;
            int d = retired - (g << 4);
            d = (d < 0) ? 0 : (d > 16 ? 16 : d);
            cumG += (unsigned)(16 - d);
            cumC += (unsigned)(8 - (j >> 7));
        }

        // ---- register-prefetch the owned trailing-row slots (overlaps phase-A sc1 round) ----
        double AR[8];
        double* __restrict__ Arow = A + (size_t)u*n + (j+1);
        if (u > j){
            #pragma unroll
            for (int q = 0; q < 8; ++q){
                int c = cbase + (q << 7);
                AR[q] = (c < m) ? Arow[c] : 0.0;
            }
        }

        // ---- fused phase A + pivot row; pv via block-local reduction ----
        double s = 0.0, wp0 = 0.0;
        if (j > 0){
            const double* __restrict__ Prow = P + (size_t)(j-1)*NN;
            const double* __restrict__ rs   = Rst + ((size_t)(j & 1) << 10);
            const double p0 = gload(&Prow[0]);
            double pi = 0.0, rsi = 0.0, vp = 0.0, pvp = 0.0;
            const bool act = (tid <= m);
            if (act){
                pi = gload(&Prow[tid]);
                if (tid >= 1){ rsi = gload(&rs[tid]); vp = VJold[tid]*sc_p; }
                else vp = 1.0;
                pvp = pi*vp;
            }
            double t = pvp;
            #pragma unroll
            for (int o = 32; o; o >>= 1) t += __shfl_down(t, o);
            if (lane == 0) redA[wid] = t;
            __syncthreads();
            double pv = 0.0;
            #pragma unroll
            for (int i = 0; i < 16; ++i) pv += redA[i];
            const double c2 = 0.5*tau_p*tau_p*pv;
            wp0 = tau_p*p0 - c2;
            if (act){
                double wp = tau_p*pi - c2*vp;
                VP[tid] = vp; WP[tid] = wp;
                if (tid >= 1){
                    double x = rsi - wp - wp0*vp;
                    VJnew[tid-1] = x;
                    if (tid >= 2) s += x*x;
                }
            }
        } else {
            if (tid < m){
                double x = A[1 + tid];   // row 0, fresh from build_A_k
                VJnew[tid] = x;
                if (tid >= 1) s += x*x;
            }
        }
        #pragma unroll
        for (int o = 32; o; o >>= 1) s += __shfl_down(s, o);
        if (lane == 0) redB[wid] = s;
        __syncthreads();     // VP/WP/VJnew visible + redB ready

        double sigma2 = 0.0;
        #pragma unroll
        for (int i = 0; i < 16; ++i) sigma2 += redB[i];
        double alpha = VJnew[0];
        double beta, tl, sc;
        if (sigma2 == 0.0){ beta = alpha; tl = 0.0; sc = 0.0; }
        else {
            beta = -copysign(sqrt(alpha*alpha + sigma2), alpha);
            tl = (beta - alpha)/beta;
            sc = 1.0/(alpha - beta);
        }

        // ---- owner-block writeback of row j ----
        if (bid == (j >> 3)){
            double* __restrict__ row = A + (size_t)j*n + (j+1);
            if (tid < m) row[tid] = VJnew[tid];
            if (tid == 0){
                e[j] = beta; tauA[j] = tl; sclA[j] = sc;
                if (j > 0) A[(size_t)j*n + j] -= 2.0*wp0;
            }
        }

        // ---- phase B: owner-private trailing update (from registers) + matvec; publish pivot ----
        if (u > j){
            const int r = u - (j+1);
            double* __restrict__ rs_w = Rst + ((size_t)((j+1) & 1) << 10);
            const bool pub = (r == 0);
            double acc = 0.0;
            if (j > 0){
                double vpr = VP[1+r], wpr = WP[1+r];
                #pragma unroll
                for (int q = 0; q < 8; ++q){
                    int c = cbase + (q << 7);
                    if (c < m){
                        double a = AR[q] - (vpr*WP[1+c] + wpr*VP[1+c]);
                        Arow[c] = a;
                        if (pub) gstore(&rs_w[c], a);
                        double vj = (c == 0) ? 1.0 : VJnew[c]*sc;
                        acc += a*vj;
                    }
                }
            } else {
                #pragma unroll
                for (int q = 0; q < 8; ++q){
                    int c = cbase + (q << 7);
                    if (c < m){
                        double a = AR[q];
                        if (pub) gstore(&rs_w[c], a);
                        double vj = (c == 0) ? 1.0 : VJnew[c]*sc;
                        acc += a*vj;
                    }
                }
            }
            #pragma unroll
            for (int o = 32; o; o >>= 1) acc += __shfl_down(acc, o);
            if (lane == 0)
                atomicAdd(&P[(size_t)j*NN + r], acc);
        }
        __syncthreads();     // each wave's vmcnt(0) drains its P atomics/Rst stores before tid0 arrives

        if (tid == 0){
            unsigned t = __hip_atomic_fetch_add(&bar[g*32], 1u, __ATOMIC_RELAXED, __HIP_MEMORY_SCOPE_AGENT);
            if (t == cumG - 1u)
                __hip_atomic_fetch_add(&bar[256], 1u, __ATOMIC_RELAXED, __HIP_MEMORY_SCOPE_AGENT);
            if (j != mylast){
                while (__hip_atomic_load(&bar[256], __ATOMIC_RELAXED, __HIP_MEMORY_SCOPE_AGENT) < cumC)
                    __builtin_amdgcn_s_sleep(1);
            }
        }
        if (j == mylast) break;    // retired (block-uniform)
        __syncthreads();           // release after spin
        tau_p = tl; sc_p = sc;
    }

    // ---- final pending update (column jend-1) on the TB x TB tail, owner-only ----
    if (bid >= (jend >> 3)){
        const int tb = n - jend;
        const double* __restrict__ VJf = VJ2[(jend-1) & 1];
        const double* __restrict__ pp  = P + (size_t)(jend-1)*NN;
        double pvp = 0.0;
        if (tid < tb){
            double pi = gload(&pp[tid]);
            double v = (tid == 0) ? 1.0 : VJf[tid]*sc_p;
            pvp = pi*v;
        }
        #pragma unroll
        for (int o = 32; o; o >>= 1) pvp += __shfl_down(pvp, o);
        if (lane == 0) redA[wid] = pvp;
        __syncthreads();
        double pv = 0.0;
        #pragma unroll
        for (int i = 0; i < 16; ++i) pv += redA[i];
        double c2f = 0.5*tau_p*tau_p*pv;
        if (u >= jend){
            const int ri = u - jend;
            double vpr = (ri == 0) ? 1.0 : VJf[ri]*sc_p;
            double wpr = tau_p*gload(&pp[ri]) - c2f*vpr;
            double* __restrict__ Ar = A + (size_t)u*n + jend;
            for (int ci = half*64 + lane; ci < tb; ci += 128){
                double vpc = (ci == 0) ? 1.0 : VJf[ci]*sc_p;
                double wpc = tau_p*gload(&pp[ci]) - c2f*vpc;
                Ar[ci] -= vpr*wpc + wpr*vpc;
            }
        }
    }
}

// Tail: remaining (TB-2) Householder steps entirely in LDS (single block).
__global__ __launch_bounds__(256) void hh_tail(double* __restrict__ A64, double* __restrict__ e,
                                               double* __restrict__ tau, double* __restrict__ scaleg, int n)
{
    __shared__ double T[TB][TB+2];
    __shared__ double v[TB], p[TB], red[256];
    const int base = n - TB;
    const int tid = threadIdx.x;
    for (int t = tid; t < TB*TB; t += 256){
        int r = t / TB, c = t % TB;
        T[r][c] = A64[(size_t)(base + r)*n + base + c];
    }
    __syncthreads();
    for (int l = 0; l <= TB - 3; ++l){
        const int m = TB - 1 - l;
        double s = 0.0;
        for (int i = 1 + tid; i < m; i += 256){ double x = T[l+1+i][l]; s += x*x; }
        red[tid] = s; __syncthreads();
        for (int o = 128; o; o >>= 1){ if (tid < o) red[tid] += red[tid + o]; __syncthreads(); }
        double sigma2 = red[0];
        double alpha = T[l+1][l];
        double beta, tl, sc;
        if (sigma2 == 0.0){ beta = alpha; tl = 0.0; sc = 0.0; }
        else {
            beta = -copysign(sqrt(alpha*alpha + sigma2), alpha);
            tl = (beta - alpha)/beta;
            sc = 1.0/(alpha - beta);
        }
        for (int i = tid; i < m; i += 256) v[i] = (i == 0) ? 1.0 : T[l+1+i][l]*sc;
        __syncthreads();
        for (int i = tid; i < m; i += 256){
            double acc = 0.0;
            for (int c = 0; c < m; ++c) acc += T[l+1+i][l+1+c]*v[c];
            p[i] = acc;
        }
        __syncthreads();
        double s2 = 0.0;
        for (int i = tid; i < m; i += 256) s2 += p[i]*v[i];
        red[tid] = s2; __syncthreads();
        for (int o = 128; o; o >>= 1){ if (tid < o) red[tid] += red[tid + o]; __syncthreads(); }
        double pvv = red[0];
        double c2 = 0.5*tl*tl*pvv;
        for (int t2 = tid; t2 < m*m; t2 += 256){
            int r = t2 / m, c = t2 % m;
            double wr = tl*p[r] - c2*v[r];
            double wc = tl*p[c] - c2*v[c];
            T[l+1+r][l+1+c] -= v[r]*wc + wr*v[c];
        }
        if (tid == 0){ int j = base + l; e[j] = beta; tau[j] = tl; scaleg[j] = 1.0; }
        for (int i = tid; i < m; i += 256) A64[(size_t)(base + l)*n + (base + l + 1) + i] = v[i];
        __syncthreads();
    }
    for (int r = tid; r < TB; r += 256) A64[(size_t)(base + r)*n + base + r] = T[r][r];
    if (tid == 0) A64[(size_t)(n-1)*n + (n-2)] = T[TB-1][TB-2];
}

__global__ __launch_bounds__(256) void extract_de_k(const double* __restrict__ A64, double* __restrict__ d,
                                                    double* __restrict__ e, int n)
{
    int i = blockIdx.x*256 + threadIdx.x;
    if (i < n) d[i] = A64[(size_t)i*n + i];
    if (i == 0) e[n-2] = A64[(size_t)(n-1)*n + (n-2)];
}

// ============================ tridiagonal eigensolver ============================
__global__ __launch_bounds__(256) void bisect_k(const double* __restrict__ d, const double* __restrict__ e,
                                                double* __restrict__ w, int n)
{
    __shared__ double ds[1024], e2s[1024];
    const int tid = threadIdx.x;
    for (int i = tid; i < n; i += 256) ds[i] = d[i];
    for (int i = tid; i < n-1; i += 256){ double ei = e[i]; e2s[i] = ei*ei; }
    __syncthreads();
    int k = blockIdx.x*256 + tid;
    if (k >= n) return;
    double gl = 1e300, gu = -1e300;
    for (int i = 0; i < n; ++i){
        double em = (i > 0) ? sqrt(e2s[i-1]) : 0.0, ep2 = (i < n-1) ? sqrt(e2s[i]) : 0.0;
        double lo2 = ds[i] - em - ep2, hi2 = ds[i] + em + ep2;
        gl = fmin(gl, lo2); gu = fmax(gu, hi2);
    }
    double lo = gl - 1e-10, hi = gu + 1e-10;
    for (int it = 0; it < 42; ++it){
        double mid = 0.5*(lo + hi);
        int cnt = 0;
        double p0 = 1.0;
        double p1 = ds[0] - mid;
        if (p1 <= 0.0){ ++cnt; if (p1 == 0.0) p1 = -1e-300; }
        for (int i = 1; i < n; ++i){
            double pn = (ds[i] - mid)*p1 - e2s[i-1]*p0;
            bool neg = ((pn < 0.0) != (p1 < 0.0)) || (pn == 0.0);
            cnt += neg;
            if (pn == 0.0) pn = (p1 > 0.0) ? -1e-300 : 1e-300;
            p0 = p1; p1 = pn;
            double ap = fabs(p1);
            if (ap > 1e120){ p1 *= 1e-200; p0 *= 1e-200; }
            else if (ap < 1e-120){ p1 *= 1e200; p0 *= 1e200; }
        }
        if (cnt <= k) lo = mid; else hi = mid;
    }
    w[k] = 0.5*(lo + hi);
}

// Inverse iteration; 16-deep load prefetch in the dependent solve passes.
__global__ __launch_bounds__(256) void invit_k(const double* __restrict__ d, const double* __restrict__ e,
                                               const double* __restrict__ w,
                                               double* __restrict__ FD, double* __restrict__ FL,
                                               double* __restrict__ FU, double* __restrict__ FU2,
                                               signed char* __restrict__ PIV, double* __restrict__ Z, int n)
{
    __shared__ double dsm[1024], esm[1024];
    const int tid = threadIdx.x;
    for (int i = tid; i < n; i += 256) dsm[i] = d[i];
    for (int i = tid; i < n-1; i += 256) esm[i] = e[i];
    __syncthreads();
    int k = blockIdx.x*256 + tid;
    if (k >= n) return;
    const double lam = w[k];
    const double tiny = 1e-280;
    double dcur = dsm[0] - lam;
    double ucur = esm[0];
    for (int i = 0; i < n-1; ++i){
        double dli = esm[i];
        double dnext_init = dsm[i+1] - lam;
        double unext_init = (i < n-2) ? esm[i+1] : 0.0;
        size_t o = (size_t)i*n + k;
        if (fabs(dcur) >= fabs(dli)){
            if (dcur == 0.0) dcur = tiny;
            double f = dli/dcur;
            FD[o] = dcur; FL[o] = f; FU[o] = ucur; FU2[o] = 0.0; PIV[o] = 0;
            dcur = dnext_init - f*ucur;
            ucur = unext_init;
        } else {
            double f = dcur/dli;
            FD[o] = dli; FL[o] = f; FU[o] = dnext_init; FU2[o] = unext_init; PIV[o] = 1;
            dcur = ucur - f*dnext_init;
            ucur = -f*unext_init;
        }
    }
    if (dcur == 0.0) dcur = tiny;
    FD[(size_t)(n-1)*n + k] = dcur;
    for (int i = 0; i < n; ++i){
        unsigned h = (unsigned)(i + 1)*0x9E3779B9u + (unsigned)(k + 1)*0x85EBCA6Bu;
        h ^= h >> 16; h *= 0x7FEB352Du; h ^= h >> 15; h *= 0x846CA68Bu; h ^= h >> 16;
        Z[(size_t)i*n + k] = (double)(h >> 8)*(1.0/16777216.0) - 0.5;
    }
    const double fdlast = FD[(size_t)(n-1)*n + k];
    for (int iter = 0; iter < 2; ++iter){
        // ---- forward substitution (prefetch-16) ----
        double zc = Z[k];
        int i = 0;
        const int nm1 = n - 1;
        for (; i + 16 <= nm1; i += 16){
            double fl[16], zn[16]; int pv[16];
            #pragma unroll
            for (int u2 = 0; u2 < 16; ++u2){
                size_t o = (size_t)(i+u2)*n + k;
                fl[u2] = FL[o]; zn[u2] = Z[o + n]; pv[u2] = PIV[o];
            }
            #pragma unroll
            for (int u2 = 0; u2 < 16; ++u2){
                size_t o = (size_t)(i+u2)*n + k;
                if (!pv[u2]){ Z[o] = zc; zc = zn[u2] - fl[u2]*zc; }
                else        { Z[o] = zn[u2]; zc = zc - fl[u2]*zn[u2]; }
            }
        }
        for (; i < nm1; ++i){
            size_t o = (size_t)i*n + k;
            double fl = FL[o], zn = Z[o + n];
            if (!PIV[o]){ Z[o] = zc; zc = zn - fl*zc; }
            else        { Z[o] = zn; zc = zc - fl*zn; }
        }
        // ---- backward substitution (prefetch-16) ----
        double za = zc / fdlast;
        Z[(size_t)(n-1)*n + k] = za;
        size_t o2 = (size_t)(n-2)*n + k;
        double zaa = (Z[o2] - FU[o2]*za) / FD[o2];
        Z[o2] = zaa;
        double zb = za;
        int i2 = n - 3;
        for (; i2 >= 15; i2 -= 16){
            double zv[16], fu[16], fu2v[16], fd[16];
            #pragma unroll
            for (int u2 = 0; u2 < 16; ++u2){
                size_t o = (size_t)(i2-u2)*n + k;
                zv[u2] = Z[o]; fu[u2] = FU[o]; fu2v[u2] = FU2[o]; fd[u2] = FD[o];
            }
            #pragma unroll
            for (int u2 = 0; u2 < 16; ++u2){
                size_t o = (size_t)(i2-u2)*n + k;
                double znew = (zv[u2] - fu[u2]*zaa - fu2v[u2]*zb) / fd[u2];
                Z[o] = znew;
                zb = zaa; zaa = znew;
            }
        }
        for (; i2 >= 0; --i2){
            size_t o = (size_t)i2*n + k;
            double znew = (Z[o] - FU[o]*zaa - FU2[o]*zb) / FD[o];
            Z[o] = znew;
            zb = zaa; zaa = znew;
        }
        // ---- max-normalize (prefetch-8) ----
        double m0=0,m1=0,m2=0,m3=0,m4=0,m5=0,m6=0,m7=0;
        int i3 = 0;
        for (; i3 + 8 <= n; i3 += 8){
            m0 = fmax(m0, fabs(Z[(size_t)(i3+0)*n + k]));
            m1 = fmax(m1, fabs(Z[(size_t)(i3+1)*n + k]));
            m2 = fmax(m2, fabs(Z[(size_t)(i3+2)*n + k]));
            m3 = fmax(m3, fabs(Z[(size_t)(i3+3)*n + k]));
            m4 = fmax(m4, fabs(Z[(size_t)(i3+4)*n + k]));
            m5 = fmax(m5, fabs(Z[(size_t)(i3+5)*n + k]));
            m6 = fmax(m6, fabs(Z[(size_t)(i3+6)*n + k]));
            m7 = fmax(m7, fabs(Z[(size_t)(i3+7)*n + k]));
        }
        double mx = fmax(fmax(fmax(m0,m1),fmax(m2,m3)), fmax(fmax(m4,m5),fmax(m6,m7)));
        for (; i3 < n; ++i3) mx = fmax(mx, fabs(Z[(size_t)i3*n + k]));
        double s = (mx > 0.0) ? 1.0/mx : 1.0;
        for (int i4 = 0; i4 + 8 <= n; i4 += 8){
            double zv[8];
            #pragma unroll
            for (int u2 = 0; u2 < 8; ++u2) zv[u2] = Z[(size_t)(i4+u2)*n + k];
            #pragma unroll
            for (int u2 = 0; u2 < 8; ++u2) Z[(size_t)(i4+u2)*n + k] = zv[u2]*s;
        }
    }
    // ---- 2-norm normalize (prefetch-8) ----
    double n0=0,n1=0,n2=0,n3=0,n4=0,n5=0,n6=0,n7=0;
    int i5 = 0;
    for (; i5 + 8 <= n; i5 += 8){
        double zv[8];
        #pragma unroll
        for (int u2 = 0; u2 < 8; ++u2) zv[u2] = Z[(size_t)(i5+u2)*n + k];
        n0 += zv[0]*zv[0]; n1 += zv[1]*zv[1]; n2 += zv[2]*zv[2]; n3 += zv[3]*zv[3];
        n4 += zv[4]*zv[4]; n5 += zv[5]*zv[5]; n6 += zv[6]*zv[6]; n7 += zv[7]*zv[7];
    }
    double nrm = ((n0+n1)+(n2+n3)) + ((n4+n5)+(n6+n7));
    for (; i5 < n; ++i5){ double v = Z[(size_t)i5*n + k]; nrm += v*v; }
    double s = 1.0/sqrt(nrm);
    for (int i6 = 0; i6 + 8 <= n; i6 += 8){
        double zv[8];
        #pragma unroll
        for (int u2 = 0; u2 < 8; ++u2) zv[u2] = Z[(size_t)(i6+u2)*n + k];
        #pragma unroll
        for (int u2 = 0; u2 < 8; ++u2) Z[(size_t)(i6+u2)*n + k] = zv[u2]*s;
    }
}

// ============================ batched blocked-WY back-transform ============================
__global__ __launch_bounds__(256) void wy_buildV_k(const double* __restrict__ A64, const double* __restrict__ scaleg,
                                                   double* __restrict__ Vbig, int n)
{
    size_t idx = (size_t)blockIdx.x*256 + threadIdx.x;
    if (idx >= (size_t)NWY*1024*64) return;
    int g = (int)(idx >> 16);
    int r = (int)((idx >> 6) & 1023);
    int t = (int)(idx & 63);
    int b0 = g*64;
    int nbsz = (n - 2) - b0; if (nbsz > 64) nbsz = 64;
    double v = 0.0;
    if (t < nbsz){
        int j = b0 + t;
        if (r == j + 1) v = 1.0;
        else if (r > j + 1) v = A64[(size_t)j*n + r]*scaleg[j];
    }
    Vbig[idx] = v;
}

__global__ __launch_bounds__(256) void wy_buildT_k(const double* __restrict__ Vbig, const double* __restrict__ tau,
                                                   double* __restrict__ Tbig, int n)
{
    __shared__ double G[64][65];
    __shared__ double Ts[64][65];
    __shared__ double Vs[32][65];
    const int g = blockIdx.x;
    const int tid = threadIdx.x;
    const double* __restrict__ V = Vbig + ((size_t)g << 16);
    const int b0 = g*64;
    int nbsz = (n - 2) - b0; if (nbsz > 64) nbsz = 64;
    for (int p = tid; p < 64*64; p += 256) G[p >> 6][p & 63] = 0.0;
    __syncthreads();
    for (int rb = b0; rb < n; rb += 32){
        for (int s = tid; s < 2048; s += 256){
            int rr = s >> 6, tt = s & 63;
            Vs[rr][tt] = V[((size_t)(rb + rr) << 6) + tt];
        }
        __syncthreads();
        for (int p = tid; p < 4096; p += 256){
            int t = p >> 6, s2 = p & 63;
            if (t < s2 && s2 < nbsz){
                double acc = 0.0;
                #pragma unroll 8
                for (int rr = 0; rr < 32; ++rr) acc += Vs[rr][t]*Vs[rr][s2];
                G[t][s2] += acc;
            }
        }
        __syncthreads();
    }
    for (int t = nbsz - 1; t >= 0; --t){
        for (int u = tid; u < 64; u += 256){
            double val = 0.0;
            if (u == t) val = tau[b0 + t];
            else if (u > t && u < nbsz){
                double s = 0.0;
                for (int s2 = t + 1; s2 <= u; ++s2) s += G[t][s2]*Ts[s2][u];
                val = -tau[b0 + t]*s;
            }
            Ts[t][u] = val;
        }
        __syncthreads();
    }
    for (int p = tid; p < 64*64; p += 256){
        int t = p >> 6, u = p & 63;
        Tbig[((size_t)g << 12) + p] = (t < nbsz) ? Ts[t][u] : 0.0;
    }
}

// 1024-thread WY apply: 64-row chunks, one (t,c) pair per thread.
__global__ __launch_bounds__(1024) void wy_apply_k(const double* __restrict__ Vbig, const double* __restrict__ Tbig,
                                                   double* __restrict__ Z, int n)
{
    __shared__ double Vs[64][65];
    __shared__ double Zs[64][17];
    __shared__ double Y[64][17];
    __shared__ double W[64][17];
    const int tid = threadIdx.x;        // 0..1023
    const int c   = tid & 15;
    const int tq  = tid >> 4;           // 0..63
    const int c0  = blockIdx.x * 16;

    for (int g = NWY - 1; g >= 0; --g){
        const double* __restrict__ V = Vbig + ((size_t)g << 16);
        const double* __restrict__ T = Tbig + ((size_t)g << 12);
        const int b0 = g*64;
        double acc = 0.0;
        for (int rb = b0; rb < n; rb += 64){
            for (int s = tid; s < 4096; s += 1024){
                int rr = s >> 6, tt = s & 63;
                Vs[rr][tt] = V[((size_t)(rb + rr) << 6) + tt];
            }
            {
                int rr = tid >> 4, cc = tid & 15;
                Zs[rr][cc] = Z[(size_t)(rb + rr)*n + c0 + cc];
            }
            __syncthreads();
            #pragma unroll 8
            for (int rr = 0; rr < 64; ++rr)
                acc += Vs[rr][tq]*Zs[rr][c];
            __syncthreads();
        }
        Y[tq][c] = acc;
        __syncthreads();
        {
            double a = 0.0;
            for (int s = tq; s < 64; ++s) a += T[(tq << 6) + s]*Y[s][c];
            W[tq][c] = a;
        }
        __syncthreads();
        for (int rb = b0; rb < n; rb += 64){
            for (int s = tid; s < 4096; s += 1024){
                int rr = s >> 6, tt = s & 63;
                Vs[rr][tt] = V[((size_t)(rb + rr) << 6) + tt];
            }
            __syncthreads();
            {
                int rr = tid >> 4, cc = tid & 15;
                double s2 = 0.0;
                #pragma unroll 16
                for (int t = 0; t < 64; ++t) s2 += Vs[rr][t]*W[t][cc];
                Z[(size_t)(rb + rr)*n + c0 + cc] -= s2;
            }
            __syncthreads();
        }
        __syncthreads();
    }
}

// ============================ host dispatch helpers ============================
static void gemmf32(hipStream_t st, int epi,
                    const float* A, const float* B, float* C, int M, int N, int K,
                    const float* bias, const float* D)
{
    if ((K & 15) == 0 && (N & 7) == 0){
        if (M >= 768){
            dim3 g((N + 127)/128, (M + 127)/128), b(256);
            switch (epi){
            case EPI_NONE:      gemm128db<EPI_NONE><<<g, b, 0, st>>>(A, B, C, M, N, K, bias, D); break;
            case EPI_BIAS:      gemm128db<EPI_BIAS><<<g, b, 0, st>>>(A, B, C, M, N, K, bias, D); break;
            case EPI_BIAS_ADD:  gemm128db<EPI_BIAS_ADD><<<g, b, 0, st>>>(A, B, C, M, N, K, bias, D); break;
            case EPI_ABS_DIAG1: gemm128db<EPI_ABS_DIAG1><<<g, b, 0, st>>>(A, B, C, M, N, K, bias, D); break;
            case EPI_RELU:      gemm128db<EPI_RELU><<<g, b, 0, st>>>(A, B, C, M, N, K, bias, D); break;
            }
        } else {
            dim3 g((N + 127)/128, (M + 63)/64), b(128);
            switch (epi){
            case EPI_NONE:      gemm_db<EPI_NONE><<<g, b, 0, st>>>(A, B, C, M, N, K, bias, D); break;
            case EPI_BIAS:      gemm_db<EPI_BIAS><<<g, b, 0, st>>>(A, B, C, M, N, K, bias, D); break;
            case EPI_BIAS_ADD:  gemm_db<EPI_BIAS_ADD><<<g, b, 0, st>>>(A, B, C, M, N, K, bias, D); break;
            case EPI_ABS_DIAG1: gemm_db<EPI_ABS_DIAG1><<<g, b, 0, st>>>(A, B, C, M, N, K, bias, D); break;
            case EPI_RELU:      gemm_db<EPI_RELU><<<g, b, 0, st>>>(A, B, C, M, N, K, bias, D); break;
            }
        }
    } else {
        dim3 g((N + 63)/64, (M + 63)/64), b(256);
        switch (epi){
        case EPI_NONE:      gemm32<EPI_NONE><<<g, b, 0, st>>>(A, B, C, M, N, K, bias, D); break;
        case EPI_BIAS:      gemm32<EPI_BIAS><<<g, b, 0, st>>>(A, B, C, M, N, K, bias, D); break;
        case EPI_BIAS_ADD:  gemm32<EPI_BIAS_ADD><<<g, b, 0, st>>>(A, B, C, M, N, K, bias, D); break;
        case EPI_ABS_DIAG1: gemm32<EPI_ABS_DIAG1><<<g, b, 0, st>>>(A, B, C, M, N, K, bias, D); break;
        case EPI_RELU:      gemm32<EPI_RELU><<<g, b, 0, st>>>(A, B, C, M, N, K, bias, D); break;
        }
    }
}

// ============================ kernel_launch ============================
extern "C" void kernel_launch(void* const* d_in, const int* in_sizes, int n_in,
                              void* d_out, int out_size, void* d_ws, size_t ws_size,
                              hipStream_t stream)
{
    (void)in_sizes; (void)n_in; (void)out_size; (void)ws_size;
    const float* lr       = (const float*)d_in[0];
    const float* gsr_w    = (const float*)d_in[1];
    const float* start_w  = (const float*)d_in[2];
    const float* start_b  = (const float*)d_in[3];
    const float* down_w   = (const float*)d_in[4];
    const float* down_b   = (const float*)d_in[5];
    const float* pool_w   = (const float*)d_in[6];
    const float* pool_b   = (const float*)d_in[7];
    const float* bottom_w = (const float*)d_in[8];
    const float* bottom_b = (const float*)d_in[9];
    const float* end_w    = (const float*)d_in[10];
    const float* end_b    = (const float*)d_in[11];
    const float* up_w     = (const float*)d_in[12];
    const float* up_b     = (const float*)d_in[13];
    const float* gc1      = (const float*)d_in[14];
    const float* gc2      = (const float*)d_in[15];

    float* out_z     = (float*)d_out;                       // [2048,2048]
    float* out_net   = out_z + (size_t)HRD*HRD;             // [1024,2048]
    float* out_start = out_net + (size_t)NN*HRD;            // [1024,320]
    float* out_adj   = out_start + (size_t)NN*DIMF;         // [2048,2048]

    static const int LVL_N[4] = {1024, 921, 644, 386};
    static const int LVL_K[4] = {921, 644, 386, 193};

    // -------- workspace arena --------
    char* Wb = (char*)d_ws;
    size_t off = 0;
    auto alloc = [&](size_t bb)->char*{ char* p = Wb + off; off = (off + bb + 255) & ~(size_t)255; return p; };

    float*  A32  = (float*) alloc((size_t)NN*NN*4);
    double* A64  = (double*)alloc((size_t)NN*NN*8);
    float*  UfT  = (float*) alloc((size_t)NN*NN*4);   // U^T as [k][j] fp32
    double* r64  = (double*)alloc(NN*8);
    double* dD   = (double*)alloc(NN*8);
    double* dE   = (double*)alloc(NN*8);
    double* dTau = (double*)alloc(NN*8);
    double* dScl = (double*)alloc(NN*8);
    double* dWev = (double*)alloc(NN*8);
    double* pvA  = (double*)alloc(NN*8);              // kept (init target), unused by coop8
    double* Rst  = (double*)alloc((size_t)2*NN*8);    // double-buffered pivot-row stage (sc1)
    unsigned* barcnt = (unsigned*)alloc(8192);
    char* SBASE = Wb + off;

    // P2 overlay (U-Net)
    size_t so = 0;
    auto salloc = [&](size_t bb)->char*{ char* p = SBASE + so; so = (so + bb + 255) & ~(size_t)255; return p; };
    float* XT  = (float*)salloc((size_t)NN*DIMF*4);
    float* XP1 = (float*)salloc((size_t)NN*DIMF*4);
    float* XP2 = (float*)salloc((size_t)NN*DIMF*4);
    float* XU  = (float*)salloc((size_t)NN*DIMF*4);
    float* DN[4]; for (int l = 0; l < 4; ++l) DN[l] = (float*)salloc((size_t)NN*DIMF*4);
    float* Asub[4];
    for (int l = 0; l < 4; ++l) Asub[l] = (float*)salloc((size_t)LVL_K[l]*LVL_K[l]*4);
    float* SC = (float*)salloc(NN*4);
    int*   IDX[4]; for (int l = 0; l < 4; ++l) IDX[l] = (int*)salloc(NN*4);
    float* VAL[4]; for (int l = 0; l < 4; ++l) VAL[l] = (float*)salloc(NN*4);
    float* XC  = (float*)salloc((size_t)NN*2*DIMF*4);
    float* AXC = (float*)salloc((size_t)NN*2*DIMF*4);

    // P3 overlay (eigensolver scratch)
    const size_t PL = (size_t)NN*NN*8;
    double* Z64 = (double*)(SBASE);
    double* FD  = (double*)(SBASE + PL);       // doubles as Pmat during sytrd, Vbig during WY
    double* FL  = (double*)(SBASE + 2*PL);     // doubles as Tbig during WY
    double* FU  = (double*)(SBASE + 3*PL);
    double* FU2 = (double*)(SBASE + 4*PL);
    signed char* FPIV = (signed char*)(SBASE + 5*PL);
    double* Pmat = FD;
    double* Vbig = FD;
    double* Tbig = FL;

    // P4 overlay (GSR / refinement)
    const size_t MB8  = (size_t)HRD*NN*4;    // 8 MiB
    const size_t MB16 = (size_t)HRD*HRD*4;   // 16 MiB
    float* P4a   = (float*)(SBASE);
    float* P4t1  = (float*)(SBASE + MB8);
    float* P4adT = (float*)(SBASE);
    float* P4Zb  = (float*)(SBASE + MB16);
    float* P4ZG  = (float*)(SBASE);
    float* P4h1  = (float*)(SBASE + MB8);
    float* P4HG  = (float*)(SBASE + MB16);
    float* P4h2  = (float*)(SBASE);

    // =============== P1: normalized adjacency ===============
    rowsum_rsqrt_k<<<NN, 256, 0, stream>>>(lr, r64, NN);
    build_A_k<<<(NN*NN + 255)/256, 256, 0, stream>>>(lr, r64, A32, A64, NN);

    // =============== P2: graph U-Net (fp32) ===============
    gemmf32(stream, EPI_BIAS, A32, start_w, out_start, NN, DIMF, NN, start_b, nullptr);

    const float* Xcur = out_start;
    const float* Acur = A32;
    float* ping = XP1; float* pong = XP2;
    for (int l = 0; l < 4; ++l){
        int nl = LVL_N[l], kl = LVL_K[l];
        gemmf32(stream, EPI_NONE, Acur, Xcur, XT, nl, DIMF, nl, nullptr, nullptr);
        gemmf32(stream, EPI_BIAS, XT, down_w + (size_t)l*DIMF*DIMF, DN[l], nl, DIMF, DIMF,
                down_b + (size_t)l*DIMF, nullptr);
        score_k<<<(nl + 3)/4, 256, 0, stream>>>(DN[l], pool_w + (size_t)l*DIMF, pool_b + l, SC, nl, DIMF);
        topk_k<<<1, 256, 0, stream>>>(SC, nl, kl, IDX[l], VAL[l]);
        gatherX_k<<<(unsigned)(((size_t)kl*DIMF + 255)/256), 256, 0, stream>>>(DN[l], IDX[l], VAL[l], ping, kl, DIMF);
        gatherA_k<<<(unsigned)(((size_t)kl*kl + 255)/256), 256, 0, stream>>>(Acur, IDX[l], Asub[l], kl, nl);
        Xcur = ping; Acur = Asub[l];
        float* t = ping; ping = pong; pong = t;
    }
    gemmf32(stream, EPI_NONE, Acur, Xcur, XT, 193, DIMF, 193, nullptr, nullptr);
    float* Xb = ping;
    gemmf32(stream, EPI_BIAS, XT, bottom_w, Xb, 193, DIMF, DIMF, bottom_b, nullptr);
    const float* Xup = Xb;
    float* upbuf[2] = { (Xb == XP1) ? XP2 : XP1, (Xb == XP1) ? XP1 : XP2 };
    for (int i2 = 0; i2 < 4; ++i2){
        int jl = 3 - i2;
        int nj = LVL_N[jl];
        int kj = LVL_K[jl];
        fill0_k<<<(unsigned)(((size_t)nj*DIMF + 255)/256), 256, 0, stream>>>(XU, (size_t)nj*DIMF);
        scatterX_k<<<(unsigned)(((size_t)kj*DIMF + 255)/256), 256, 0, stream>>>(Xup, IDX[jl], XU, kj, DIMF);
        const float* Aj = (jl == 0) ? A32 : Asub[jl - 1];
        gemmf32(stream, EPI_NONE, Aj, XU, XT, nj, DIMF, nj, nullptr, nullptr);
        float* Xn = upbuf[i2 & 1];
        gemmf32(stream, EPI_BIAS_ADD, XT, up_w + (size_t)i2*DIMF*DIMF, Xn, nj, DIMF, DIMF,
                up_b + (size_t)i2*DIMF, DN[jl]);
        Xup = Xn;
    }
    concat_k<<<(unsigned)(((size_t)NN*2*DIMF + 255)/256), 256, 0, stream>>>(Xup, out_start, XC, NN, DIMF);
    gemmf32(stream, EPI_NONE, A32, XC, AXC, NN, 2*DIMF, NN, nullptr, nullptr);
    gemmf32(stream, EPI_BIAS, AXC, end_w, out_net, NN, HRD, 2*DIMF, end_b, nullptr);

    // =============== P3: eigendecomposition of A (fp64) ===============
    const int JEND = NN - TB;
    init_sytrd_k<<<4, 256, 0, stream>>>(pvA, barcnt, NN);
    filld0_k<<<(unsigned)(((size_t)JEND*NN + 255)/256), 256, 0, stream>>>(Pmat, (size_t)JEND*NN);
    sytrd_coop8<<<CB3, BT3, 0, stream>>>(A64, dE, dTau, dScl, Pmat, Rst, barcnt, NN, JEND);
    hh_tail<<<1, 256, 0, stream>>>(A64, dE, dTau, dScl, NN);
    extract_de_k<<<4, 256, 0, stream>>>(A64, dD, dE, NN);
    bisect_k<<<4, 256, 0, stream>>>(dD, dE, dWev, NN);
    invit_k<<<4, 256, 0, stream>>>(dD, dE, dWev, FD, FL, FU, FU2, FPIV, Z64, NN);
    wy_buildV_k<<<(unsigned)(((size_t)NWY*1024*64 + 255)/256), 256, 0, stream>>>(A64, dScl, Vbig, NN);
    wy_buildT_k<<<NWY, 256, 0, stream>>>(Vbig, dTau, Tbig, NN);
    wy_apply_k<<<NN/16, 1024, 0, stream>>>(Vbig, Tbig, Z64, NN);
    {
        dim3 g(NN/32, NN/32), b(256);
        transpose_cast_k<<<g, b, 0, stream>>>(Z64, UfT, NN);
    }

    // =============== P4: GSR layer + refinement (fp32) ===============
    build_a_k<<<(unsigned)(((size_t)HRD*NN + 255)/256), 256, 0, stream>>>(gsr_w, P4a);
    gemmf32(stream, EPI_NONE, P4a, UfT, P4t1, HRD, NN, NN, nullptr, nullptr);               // a @ U^T
    gemmf32(stream, EPI_ABS_DIAG1, P4t1, out_net, out_adj, HRD, HRD, NN, nullptr, nullptr); // adj
    {
        dim3 g(HRD/32, HRD/32), b(256);
        transpose32_k<<<g, b, 0, stream>>>(out_adj, P4adT, HRD);                            // adj^T
    }
    {
        const int T = HRD >> 7;                       // 16 tiles -> 136 upper pairs
        gemm_symAAT<<<T*(T+1)/2, 256, 0, stream>>>(out_adj, P4adT, P4Zb, HRD);              // adj @ adj^T (sym)
    }
    symabs1_k<<<(unsigned)(((size_t)HRD*HRD + 255)/256), 256, 0, stream>>>(P4Zb, HRD);      // Z
    gemmf32(stream, EPI_NONE, P4Zb, gc1, P4ZG, HRD, NN, HRD, nullptr, nullptr);             // Z @ gc1
    gemmf32(stream, EPI_RELU, out_adj, P4ZG, P4h1, HRD, NN, HRD, nullptr, nullptr);         // h1
    gemmf32(stream, EPI_NONE, P4h1, gc2, P4HG, HRD, HRD, NN, nullptr, nullptr);             // h1 @ gc2
    gemmf32(stream, EPI_RELU, out_adj, P4HG, P4h2, HRD, HRD, HRD, nullptr, nullptr);        // h2
    final_z_k<<<(unsigned)(((size_t)HRD*HRD + 255)/256), 256, 0, stream>>>(P4h2, out_z, HRD); // z
}